// Round 15
// baseline (380.996 us; speedup 1.0000x reference)
//
#include <hip/hip_runtime.h>

#define S_LEN 2048
#define NH 16

typedef unsigned short u16;
typedef __attribute__((ext_vector_type(8))) short bf16x8;
typedef __attribute__((ext_vector_type(4))) short s16x4;
typedef __attribute__((ext_vector_type(4))) unsigned short u16x4;
typedef __attribute__((ext_vector_type(4))) unsigned int u32x4;
typedef __attribute__((ext_vector_type(4))) float f32x4;

__device__ __forceinline__ u16 f2bf(float f) {
  union { float f; unsigned int i; } x; x.f = f;
  unsigned int r = x.i + 0x7FFFu + ((x.i >> 16) & 1u);
  return (u16)(r >> 16);
}
__device__ __forceinline__ unsigned pk2(float lo, float hi) {
  unsigned r;
  asm("v_cvt_pk_bf16_f32 %0, %1, %2" : "=v"(r) : "v"(lo), "v"(hi));
  return r;
}
__device__ __forceinline__ void glds16(const void* g, void* l) {
  __builtin_amdgcn_global_load_lds((const __attribute__((address_space(1))) void*)g,
                                   (__attribute__((address_space(3))) void*)l, 16, 0, 0);
}

// ---------------- cast fp32 -> bf16 (weights only) ----------------
__global__ __launch_bounds__(256) void cast_f32_bf16(const float* __restrict__ in,
                                                     u16* __restrict__ out) {
  size_t i = ((size_t)blockIdx.x * 256 + threadIdx.x) * 8;
  f32x4 a = *(const f32x4*)&in[i];
  f32x4 b = *(const f32x4*)&in[i + 4];
  u32x4 o;
  o[0] = pk2(a[0], a[1]);
  o[1] = pk2(a[2], a[3]);
  o[2] = pk2(b[0], b[1]);
  o[3] = pk2(b[2], b[3]);
  *(u32x4*)&out[i] = o;
}

__global__ __launch_bounds__(256) void cast2_f32_bf16(const float* __restrict__ i0,
                                                      const float* __restrict__ i1,
                                                      u16* __restrict__ o0,
                                                      u16* __restrict__ o1) {
  const float* in = blockIdx.y ? i1 : i0;
  u16* out = blockIdx.y ? o1 : o0;
  size_t i = ((size_t)blockIdx.x * 256 + threadIdx.x) * 8;
  f32x4 a = *(const f32x4*)&in[i];
  f32x4 b = *(const f32x4*)&in[i + 4];
  u32x4 o;
  o[0] = pk2(a[0], a[1]);
  o[1] = pk2(a[2], a[3]);
  o[2] = pk2(b[0], b[1]);
  o[3] = pk2(b[2], b[3]);
  *(u32x4*)&out[i] = o;
}

// ---------------- transpose+cast: in [K,N] fp32 -> out [N,K] bf16 ----------------
__global__ __launch_bounds__(256) void transpose2_f32_bf16(const float* __restrict__ i0,
                                                           const float* __restrict__ i1,
                                                           u16* __restrict__ o0,
                                                           u16* __restrict__ o1,
                                                           int K, int N) {
  const float* in = blockIdx.z ? i1 : i0;
  u16* out = blockIdx.z ? o1 : o0;
  __shared__ u16 tile[64][72];
  int k0 = blockIdx.y * 64, n0 = blockIdx.x * 64;
  int t = threadIdx.x;
#pragma unroll
  for (int i = 0; i < 4; ++i) {
    int idx = i * 256 + t;
    int r = idx >> 4;
    int c4 = (idx & 15) << 2;
    f32x4 v = *(const f32x4*)&in[(size_t)(k0 + r) * N + n0 + c4];
#pragma unroll
    for (int j = 0; j < 4; ++j) tile[r][c4 + j] = f2bf(v[j]);
  }
  __syncthreads();
#pragma unroll
  for (int i = 0; i < 4; ++i) {
    int idx = i * 256 + t;
    int r = idx >> 4;
    int c4 = (idx & 15) << 2;
    u16x4 v;
    v[0] = tile[c4 + 0][r];
    v[1] = tile[c4 + 1][r];
    v[2] = tile[c4 + 2][r];
    v[3] = tile[c4 + 3][r];
    *(u16x4*)&out[(size_t)(n0 + r) * K + k0 + c4] = v;
  }
}

__global__ __launch_bounds__(256) void transpose_f32_bf16(const float* __restrict__ in,
                                                          u16* __restrict__ out,
                                                          int K, int N) {
  __shared__ u16 tile[64][72];
  int k0 = blockIdx.y * 64, n0 = blockIdx.x * 64;
  int t = threadIdx.x;
#pragma unroll
  for (int i = 0; i < 4; ++i) {
    int idx = i * 256 + t;
    int r = idx >> 4;
    int c4 = (idx & 15) << 2;
    f32x4 v = *(const f32x4*)&in[(size_t)(k0 + r) * N + n0 + c4];
#pragma unroll
    for (int j = 0; j < 4; ++j) tile[r][c4 + j] = f2bf(v[j]);
  }
  __syncthreads();
#pragma unroll
  for (int i = 0; i < 4; ++i) {
    int idx = i * 256 + t;
    int r = idx >> 4;
    int c4 = (idx & 15) << 2;
    u16x4 v;
    v[0] = tile[c4 + 0][r];
    v[1] = tile[c4 + 1][r];
    v[2] = tile[c4 + 2][r];
    v[3] = tile[c4 + 3][r];
    *(u16x4*)&out[(size_t)(n0 + r) * K + k0 + c4] = v;
  }
}

// ------------- absorb_q -------------
__global__ __launch_bounds__(256) void absorb_q(const u16* __restrict__ Wkr,
                                                const u16* __restrict__ Wqb,
                                                u16* __restrict__ Wq2T) {
  int kb = blockIdx.x, h = blockIdx.y;
  int t = threadIdx.x, w = t >> 6, lane = t & 63, lq = lane & 15, hi = lane >> 4;
  int k0 = kb * 128 + w * 32;
  f32x4 acc[4][2];
#pragma unroll
  for (int i = 0; i < 4; ++i)
#pragma unroll
    for (int j = 0; j < 2; ++j) acc[i][j] = (f32x4){0.f, 0.f, 0.f, 0.f};
#pragma unroll
  for (int kk = 0; kk < 4; ++kk) {
    bf16x8 a[4], bb[2];
#pragma unroll
    for (int fld = 0; fld < 4; ++fld)
      a[fld] = *(const bf16x8*)&Wkr[(fld * 16 + lq) * 128 + kk * 32 + hi * 8];
#pragma unroll
    for (int fk = 0; fk < 2; ++fk)
      bb[fk] = *(const bf16x8*)&Wqb[(size_t)(k0 + fk * 16 + lq) * 2048 + h * 128 + kk * 32 + hi * 8];
#pragma unroll
    for (int fld = 0; fld < 4; ++fld)
#pragma unroll
      for (int fk = 0; fk < 2; ++fk)
        acc[fld][fk] = __builtin_amdgcn_mfma_f32_16x16x32_bf16(a[fld], bb[fk], acc[fld][fk], 0, 0, 0);
  }
#pragma unroll
  for (int fld = 0; fld < 4; ++fld)
#pragma unroll
    for (int fk = 0; fk < 2; ++fk)
#pragma unroll
      for (int r = 0; r < 4; ++r)
        Wq2T[(size_t)(h * 64 + fld * 16 + hi * 4 + r) * 2048 + k0 + fk * 16 + lq] =
            f2bf(acc[fld][fk][r]);
}

// ------------- absorb_o -------------
__global__ __launch_bounds__(256) void absorb_o(const u16* __restrict__ WoutT,
                                                const u16* __restrict__ Wvr,
                                                u16* __restrict__ W2T) {
  int nb = blockIdx.x, h = blockIdx.y;
  int t = threadIdx.x, w = t >> 6, lane = t & 63, lq = lane & 15, hi = lane >> 4;
  int n0 = nb * 128 + w * 32;
  f32x4 acc[2][4];
#pragma unroll
  for (int i = 0; i < 2; ++i)
#pragma unroll
    for (int j = 0; j < 4; ++j) acc[i][j] = (f32x4){0.f, 0.f, 0.f, 0.f};
#pragma unroll
  for (int kk = 0; kk < 4; ++kk) {
    bf16x8 a[2], bb[4];
#pragma unroll
    for (int fn = 0; fn < 2; ++fn)
      a[fn] = *(const bf16x8*)&WoutT[(size_t)(n0 + fn * 16 + lq) * 2048 + h * 128 + kk * 32 + hi * 8];
#pragma unroll
    for (int fld = 0; fld < 4; ++fld)
      bb[fld] = *(const bf16x8*)&Wvr[(fld * 16 + lq) * 128 + kk * 32 + hi * 8];
#pragma unroll
    for (int fn = 0; fn < 2; ++fn)
#pragma unroll
      for (int fld = 0; fld < 4; ++fld)
        acc[fn][fld] = __builtin_amdgcn_mfma_f32_16x16x32_bf16(a[fn], bb[fld], acc[fn][fld], 0, 0, 0);
  }
#pragma unroll
  for (int fn = 0; fn < 2; ++fn)
#pragma unroll
    for (int fld = 0; fld < 4; ++fld)
#pragma unroll
      for (int r = 0; r < 4; ++r)
        W2T[(size_t)(n0 + fn * 16 + hi * 4 + r) * 1024 + h * 64 + fld * 16 + lq] =
            f2bf(acc[fn][fld][r]);
}

// ------------- absorb_bq (fp32) -------------
__global__ __launch_bounds__(256) void absorb_bq(const float* __restrict__ bq,
                                                 const float* __restrict__ Wkr,
                                                 float* __restrict__ bq2) {
  int n = blockIdx.x * 256 + threadIdx.x;
  int h = n >> 6, ld = n & 63;
  float s = 0.f;
#pragma unroll 8
  for (int dk = 0; dk < 128; ++dk) s += bq[h * 128 + dk] * Wkr[ld * 128 + dk];
  bq2[n] = s;
}

// ------------- proj GEMM: fp32 A direct-to-registers, DEPTH-2 A slots, B via glds16 -------------
// BM=BN=128, BK=32; B: 3 bufs x 8KB = 24KB LDS; 3 blocks/CU.
__global__ __launch_bounds__(256, 3) void gemm_projf(const float* __restrict__ A0,
                                                     const float* __restrict__ A1,
                                                     const float* __restrict__ A2,
                                                     const u16* __restrict__ W0,
                                                     const u16* __restrict__ W1,
                                                     const u16* __restrict__ W2,
                                                     const float* __restrict__ b0,
                                                     const float* __restrict__ b1,
                                                     const float* __restrict__ b2,
                                                     u16* __restrict__ C0,
                                                     u16* __restrict__ C1,
                                                     u16* __restrict__ C2) {
  const int N = 1024, K = 2048, nxl = 3, NT = 64;
  __shared__ u16 bbuf[3][128 * 32];

  int Lb = blockIdx.x;
  int xcd = Lb & 7, slot = Lb >> 3;
  int panel = ((slot >> nxl) << 3) + xcd;
  int x = slot & ((1 << nxl) - 1);
  int z = panel >> 5, y = panel & 31;

  const float* A = z == 0 ? A0 : (z == 1 ? A1 : A2);
  const u16* Wt = z == 0 ? W0 : (z == 1 ? W1 : W2);
  const float* bias = z == 0 ? b0 : (z == 1 ? b1 : b2);
  u16* C = z == 0 ? C0 : (z == 1 ? C1 : C2);

  int m0 = y * 128, n0 = x * 128;
  int t = threadIdx.x;
  int lane = t & 63, lq = lane & 15, hi = lane >> 4;
  int w = t >> 6, wm = w >> 1, wn = w & 1;

  f32x4 alo[2][4], ahi[2][4];  // [slot][im] -- depth-2, all indices compile-time
  f32x4 acc[4][4];
#pragma unroll
  for (int im = 0; im < 4; ++im)
#pragma unroll
    for (int fn = 0; fn < 4; ++fn) acc[im][fn] = (f32x4){0.f, 0.f, 0.f, 0.f};

#define LOADA(SLOT, KT)                                                              \
  do {                                                                               \
    int kb_ = (KT) * 32;                                                             \
    _Pragma("unroll") for (int im = 0; im < 4; ++im) {                               \
      const float* ap = &A[(size_t)(m0 + wm * 64 + im * 16 + lq) * K + kb_ + hi * 8];\
      alo[SLOT][im] = *(const f32x4*)ap;                                             \
      ahi[SLOT][im] = *(const f32x4*)(ap + 4);                                       \
    }                                                                                \
  } while (0)

#define STAGEB(KT)                                                                   \
  do {                                                                               \
    int kb_ = (KT) * 32;                                                             \
    u16* lB_ = &bbuf[(KT) % 3][0];                                                   \
    _Pragma("unroll") for (int i = 0; i < 2; ++i) {                                  \
      int idx = i * 256 + t, row = idx >> 2, c = idx & 3;                            \
      glds16(&Wt[(size_t)(n0 + row) * K + kb_ + ((c ^ ((row >> 1) & 3)) << 3)], lB_ + idx * 8); \
    }                                                                                \
  } while (0)

#define PHASE(TT, PAR)                                                               \
  do {                                                                               \
    bf16x8 af[4];                                                                    \
    _Pragma("unroll") for (int im = 0; im < 4; ++im) {                               \
      union { u32x4 u; bf16x8 v; } pu;                                               \
      pu.u[0] = pk2(alo[PAR][im][0], alo[PAR][im][1]);                               \
      pu.u[1] = pk2(alo[PAR][im][2], alo[PAR][im][3]);                               \
      pu.u[2] = pk2(ahi[PAR][im][0], ahi[PAR][im][1]);                               \
      pu.u[3] = pk2(ahi[PAR][im][2], ahi[PAR][im][3]);                               \
      af[im] = pu.v;                                                                 \
    }                                                                                \
    if ((TT) + 2 < NT) {                                                             \
      LOADA(PAR, (TT) + 2);                                                          \
      STAGEB((TT) + 2);                                                              \
    }                                                                                \
    const u16* lB_ = &bbuf[(TT) % 3][0];                                             \
    bf16x8 bf[4];                                                                    \
    _Pragma("unroll") for (int fn = 0; fn < 4; ++fn) {                               \
      int row = wn * 64 + fn * 16 + lq;                                              \
      bf[fn] = *(const bf16x8*)&lB_[row * 32 + ((hi ^ ((row >> 1) & 3)) << 3)];      \
    }                                                                                \
    __builtin_amdgcn_s_setprio(1);                                                   \
    _Pragma("unroll") for (int im = 0; im < 4; ++im)                                 \
      _Pragma("unroll") for (int fn = 0; fn < 4; ++fn)                               \
        acc[im][fn] = __builtin_amdgcn_mfma_f32_16x16x32_bf16(af[im], bf[fn], acc[im][fn], 0, 0, 0); \
    __builtin_amdgcn_s_setprio(0);                                                   \
    if ((TT) + 2 < NT)                                                               \
      asm volatile("s_waitcnt vmcnt(10)" ::: "memory"); /* A(t+1)+B(t+1) drained */  \
    else if ((TT) + 1 < NT)                                                          \
      asm volatile("s_waitcnt vmcnt(0)" ::: "memory");  /* tail drain */             \
    __builtin_amdgcn_s_barrier();                                                    \
  } while (0)

  // prologue: A(0), B(0), A(1), B(1); wait A0+B0 (leave A1(8)+B1(2)).
  LOADA(0, 0);
  STAGEB(0);
  LOADA(1, 1);
  STAGEB(1);
  asm volatile("s_waitcnt vmcnt(10)" ::: "memory");
  __builtin_amdgcn_s_barrier();

  for (int tt = 0; tt < NT; tt += 2) {
    PHASE(tt, 0);
    PHASE(tt + 1, 1);
  }

#pragma unroll
  for (int im = 0; im < 4; ++im)
#pragma unroll
    for (int fn = 0; fn < 4; ++fn) {
      int col = n0 + wn * 64 + fn * 16 + lq;
      float bv = bias[col];
      int rbase = m0 + wm * 64 + im * 16 + hi * 4;
#pragma unroll
      for (int r = 0; r < 4; ++r)
        C[(size_t)(rbase + r) * N + col] = f2bf(acc[im][fn][r] + bv);
    }
#undef LOADA
#undef STAGEB
#undef PHASE
}

// ------------- out-proj GEMM (bf16 A, R10-proven): BM=BN=128, BK=32, 3 bufs, vmcnt(4) -------------
__global__ __launch_bounds__(256, 3) void gemm_dp(const u16* __restrict__ A,
                                                  const u16* __restrict__ Wt,
                                                  const float* __restrict__ bias,
                                                  float* __restrict__ Cv,
                                                  int N, int K, int nxl) {
  __shared__ u16 ldsA[3][128 * 32];
  __shared__ u16 ldsB[3][128 * 32];

  int Lb = blockIdx.x;
  int xcd = Lb & 7, slot = Lb >> 3;
  int panel = ((slot >> nxl) << 3) + xcd;
  int x = slot & ((1 << nxl) - 1);
  int y = panel & 31;

  int m0 = y * 128, n0 = x * 128;
  int t = threadIdx.x;
  int lane = t & 63, lq = lane & 15, hi = lane >> 4;
  int w = t >> 6, wm = w >> 1, wn = w & 1;
  int NT = K >> 5;

  auto stage = [&](int q, int kt) {
    u16* lA = &ldsA[q][0];
    u16* lB = &ldsB[q][0];
    int kb = kt * 32;
#pragma unroll
    for (int i = 0; i < 2; ++i) {
      int idx = i * 256 + t;
      int row = idx >> 2, c = idx & 3;
      glds16(&A[(size_t)(m0 + row) * K + kb + ((c ^ ((row >> 1) & 3)) << 3)], lA + idx * 8);
    }
#pragma unroll
    for (int i = 0; i < 2; ++i) {
      int idx = i * 256 + t;
      int row = idx >> 2, c = idx & 3;
      glds16(&Wt[(size_t)(n0 + row) * K + kb + ((c ^ ((row >> 1) & 3)) << 3)], lB + idx * 8);
    }
  };

  f32x4 acc[4][4];
#pragma unroll
  for (int im = 0; im < 4; ++im)
#pragma unroll
    for (int fn = 0; fn < 4; ++fn) acc[im][fn] = (f32x4){0.f, 0.f, 0.f, 0.f};

  stage(0, 0);
  stage(1, 1);
  asm volatile("s_waitcnt vmcnt(4)" ::: "memory");
  __builtin_amdgcn_s_barrier();

  for (int tt = 0; tt < NT; ++tt) {
    int q = tt % 3;
    if (tt + 2 < NT) stage((tt + 2) % 3, tt + 2);
    const u16* lA = &ldsA[q][0];
    const u16* lB = &ldsB[q][0];
    bf16x8 bf[4];
#pragma unroll
    for (int fn = 0; fn < 4; ++fn) {
      int row = wn * 64 + fn * 16 + lq;
      bf[fn] = *(const bf16x8*)&lB[row * 32 + ((hi ^ ((row >> 1) & 3)) << 3)];
    }
    __builtin_amdgcn_s_setprio(1);
#pragma unroll
    for (int im = 0; im < 4; ++im) {
      int row = wm * 64 + im * 16 + lq;
      bf16x8 af = *(const bf16x8*)&lA[row * 32 + ((hi ^ ((row >> 1) & 3)) << 3)];
#pragma unroll
      for (int fn = 0; fn < 4; ++fn)
        acc[im][fn] = __builtin_amdgcn_mfma_f32_16x16x32_bf16(af, bf[fn], acc[im][fn], 0, 0, 0);
    }
    __builtin_amdgcn_s_setprio(0);
    if (tt + 2 < NT)
      asm volatile("s_waitcnt vmcnt(4)" ::: "memory");
    else
      asm volatile("s_waitcnt vmcnt(0)" ::: "memory");
    __builtin_amdgcn_s_barrier();
  }

#pragma unroll
  for (int im = 0; im < 4; ++im)
#pragma unroll
    for (int fn = 0; fn < 4; ++fn) {
      int col = n0 + wn * 64 + fn * 16 + lq;
      float bv = bias[col];
      int rbase = m0 + wm * 64 + im * 16 + hi * 4;
#pragma unroll
      for (int r = 0; r < 4; ++r)
        Cv[(size_t)(rbase + r) * N + col] = acc[im][fn][r] + bv;
    }
}

// ------------- transpose_lv: LV[b][s][h*64+ld] -> LVt[bh][ld][s], sigma-permuted per 32-s -------------
__global__ __launch_bounds__(256) void transpose_lv(const u16* __restrict__ LV,
                                                    u16* __restrict__ out) {
  __shared__ u16 tile[64 * 72];
  int st = blockIdx.x, bh = blockIdx.y;
  int b = bh >> 4, h = bh & 15;
  int t = threadIdx.x;
  int s0 = st * 64;
#pragma unroll
  for (int i = 0; i < 2; ++i) {
    int idx = i * 256 + t;
    int sr = idx >> 3, c8 = idx & 7;
    bf16x8 v = *(const bf16x8*)&LV[(size_t)(b * S_LEN + s0 + sr) * 1024 + h * 64 + c8 * 8];
    int pos = (sr & 32) + ((sr & 12) << 1) + ((sr & 16) >> 2) + (sr & 3);
#pragma unroll
    for (int j = 0; j < 8; ++j) tile[(c8 * 8 + j) * 72 + pos] = (u16)v[j];
  }
  __syncthreads();
  u16* ob = out + (size_t)bh * 64 * S_LEN;
#pragma unroll
  for (int i = 0; i < 2; ++i) {
    int idx = i * 256 + t;
    int ld = idx >> 3, c8 = idx & 7;
    bf16x8 v = *(const bf16x8*)&tile[ld * 72 + c8 * 8];
    *(bf16x8*)&ob[(size_t)ld * S_LEN + s0 + c8 * 8] = v;
  }
}

// ------------- latent flash attention: QBLK=64, 1024 blocks (4/CU), 32KB LDS -------------
__global__ __launch_bounds__(256) void mla_attn5(const u16* __restrict__ Qp,
                                                 const u16* __restrict__ LK,
                                                 const u16* __restrict__ LVt,
                                                 u16* __restrict__ O) {
  __shared__ u16 smem[16384];
  int Lb = blockIdx.x + blockIdx.y * 8;
  int half = Lb >> 9;
  int i0 = Lb & 511;
  int xcd = i0 & 7, ii = i0 >> 3;
  int bh = xcd * 4 + (ii & 3);
  int pr = ii >> 2;
  int qsup = half ? (31 - pr) : pr;
  int b = bh >> 4, h = bh & 15;
  int t = threadIdx.x, w = t >> 6, lane = t & 63, lq = lane & 15, hi = lane >> 4;
  int lq7 = lq & 7;

  const u16* Kb = LK + (size_t)b * S_LEN * 1024 + h * 64;
  const u16* Vb = LVt + (size_t)bh * 64 * S_LEN;
  const float scale = 0.08838834764831845f;

  auto stage = [&](int buf, int k0) {
    u16* lK = smem + buf * 4096;
    u16* lV = smem + 8192 + buf * 4096;
#pragma unroll
    for (int i = 0; i < 2; ++i) {
      int idx = i * 256 + t;
      int row = idx >> 3, c8 = idx & 7;
      glds16(Kb + (size_t)(k0 + row) * 1024 + ((c8 ^ (row & 7)) << 3), lK + idx * 8);
    }
#pragma unroll
    for (int i = 0; i < 2; ++i) {
      int idx = i * 256 + t;
      int row = idx >> 3, c8 = idx & 7;
      glds16(Vb + (size_t)row * S_LEN + k0 + ((c8 ^ (row & 7)) << 3), lV + idx * 8);
    }
  };

  int qb = qsup * 64;
  int nt = qsup + 1;
  int q0 = qb + w * 16;
  int kmax = q0 + 16;

  bf16x8 qf[2];
  {
    const u16* Qrow = Qp + (size_t)(b * S_LEN + q0 + lq) * 1024 + h * 64;
    qf[0] = *(const bf16x8*)&Qrow[hi * 8];
    qf[1] = *(const bf16x8*)&Qrow[32 + hi * 8];
  }

  f32x4 acc[4];
#pragma unroll
  for (int f = 0; f < 4; ++f) acc[f] = (f32x4){0.f, 0.f, 0.f, 0.f};
  float m = -1e30f, l = 0.f;

  stage(0, 0);
  __syncthreads();
  for (int tt = 0; tt < nt; ++tt) {
    int cur = tt & 1;
    if (tt + 1 < nt) stage(cur ^ 1, (tt + 1) * 64);
    int k0 = tt * 64;
    if (k0 < kmax) {
      const u16* lK = smem + cur * 4096;
      const u16* lV = smem + 8192 + cur * 4096;
      f32x4 sc[4];
#pragma unroll
      for (int kf = 0; kf < 4; ++kf) sc[kf] = (f32x4){0.f, 0.f, 0.f, 0.f};
      __builtin_amdgcn_s_setprio(1);
#pragma unroll
      for (int kf = 0; kf < 4; ++kf) {
        const u16* kr = lK + (kf * 16 + lq) * 64;
#pragma unroll
        for (int d0 = 0; d0 < 2; ++d0) {
          bf16x8 af = *(const bf16x8*)&kr[(((d0 << 2) + hi) ^ lq7) << 3];
          sc[kf] = __builtin_amdgcn_mfma_f32_16x16x32_bf16(af, qf[d0], sc[kf], 0, 0, 0);
        }
      }
      __builtin_amdgcn_s_setprio(0);
      int q = q0 + lq;
      float sv[16];
#pragma unroll
      for (int kf = 0; kf < 4; ++kf)
#pragma unroll
        for (int r = 0; r < 4; ++r) sv[kf * 4 + r] = sc[kf][r] * scale;
      if (k0 + 63 > q0) {
#pragma unroll
        for (int kf = 0; kf < 4; ++kf)
#pragma unroll
          for (int r = 0; r < 4; ++r)
            if (k0 + kf * 16 + hi * 4 + r > q) sv[kf * 4 + r] = -1e30f;
      }
      float tm = sv[0];
#pragma unroll
      for (int j = 1; j < 16; ++j) tm = fmaxf(tm, sv[j]);
      tm = fmaxf(tm, __shfl_xor(tm, 16));
      tm = fmaxf(tm, __shfl_xor(tm, 32));
      float p[16], ps = 0.f;
      if (__all(tm <= m + 8.f)) {
#pragma unroll
        for (int j = 0; j < 16; ++j) { p[j] = __expf(sv[j] - m); ps += p[j]; }
        ps += __shfl_xor(ps, 16);
        ps += __shfl_xor(ps, 32);
        l += ps;
      } else {
        float mnew = fmaxf(m, tm);
        float alpha = __expf(m - mnew);
#pragma unroll
        for (int j = 0; j < 16; ++j) { p[j] = __expf(sv[j] - mnew); ps += p[j]; }
        ps += __shfl_xor(ps, 16);
        ps += __shfl_xor(ps, 32);
        l = l * alpha + ps;
        m = mnew;
#pragma unroll
        for (int f = 0; f < 4; ++f) {
          acc[f][0] *= alpha; acc[f][1] *= alpha;
          acc[f][2] *= alpha; acc[f][3] *= alpha;
        }
      }
      bf16x8 pb[2];
#pragma unroll
      for (int ks = 0; ks < 2; ++ks) {
        union { u32x4 u; bf16x8 v; } pu;
#pragma unroll
        for (int wd = 0; wd < 4; ++wd) pu.u[wd] = pk2(p[ks * 8 + 2 * wd], p[ks * 8 + 2 * wd + 1]);
        pb[ks] = pu.v;
      }
      __builtin_amdgcn_s_setprio(1);
#pragma unroll
      for (int f = 0; f < 4; ++f) {
        const u16* vr = lV + (f * 16 + lq) * 64;
#pragma unroll
        for (int ks = 0; ks < 2; ++ks) {
          bf16x8 va = *(const bf16x8*)&vr[(((ks << 2) + hi) ^ lq7) << 3];
          acc[f] = __builtin_amdgcn_mfma_f32_16x16x32_bf16(va, pb[ks], acc[f], 0, 0, 0);
        }
      }
      __builtin_amdgcn_s_setprio(0);
    }
    __syncthreads();
  }
  {
    float inv = 1.f / l;
    int qloc = w * 16 + lq;
#pragma unroll
    for (int f = 0; f < 4; ++f)
#pragma unroll
      for (int r = 0; r < 4; ++r) {
        int col = f * 16 + hi * 4 + r;
        smem[qloc * 64 + (((col >> 3) ^ lq7) << 3) + (col & 7)] = f2bf(acc[f][r] * inv);
      }
  }
  __syncthreads();
#pragma unroll
  for (int i = 0; i < 2; ++i) {
    int cid = i * 256 + t;
    int q = cid >> 3, ch = cid & 7;
    bf16x8 v = *(const bf16x8*)&smem[q * 64 + ((ch ^ (q & 7)) << 3)];
    *(bf16x8*)&O[(size_t)(b * S_LEN + qb + q) * 1024 + h * 64 + (ch << 3)] = v;
  }
}

extern "C" void kernel_launch(void* const* d_in, const int* in_sizes, int n_in,
                              void* d_out, int out_size, void* d_ws, size_t ws_size,
                              hipStream_t stream) {
  const float* queries = (const float*)d_in[0];
  const float* keys    = (const float*)d_in[1];
  const float* values  = (const float*)d_in[2];
  const float* Wq      = (const float*)d_in[3];
  const float* bq      = (const float*)d_in[4];
  const float* Wlk     = (const float*)d_in[5];
  const float* blk     = (const float*)d_in[6];
  const float* Wlv     = (const float*)d_in[7];
  const float* blv     = (const float*)d_in[8];
  const float* Wkr     = (const float*)d_in[9];
  const float* Wvr     = (const float*)d_in[10];
  const float* Wout    = (const float*)d_in[11];
  const float* bout    = (const float*)d_in[12];

  u16* ws = (u16*)d_ws;
  u16* WqBf  = ws; ws += (size_t)2048 * 2048;
  u16* WkrBf = ws; ws += 64 * 128;
  u16* WvrBf = ws; ws += 64 * 128;
  u16* WoutT = ws; ws += (size_t)2048 * 2048;
  u16* WlkT  = ws; ws += (size_t)1024 * 2048;
  u16* WlvT  = ws; ws += (size_t)1024 * 2048;
  u16* Wq2T  = ws; ws += (size_t)1024 * 2048;
  u16* W2T   = ws; ws += (size_t)2048 * 1024;
  float* bq2 = (float*)ws; ws += 2048;
  u16* Qp    = ws; ws += (size_t)4096 * 1024;
  u16* LKb   = ws; ws += (size_t)4096 * 1024;
  u16* LVb   = ws; ws += (size_t)4096 * 1024;
  u16* LVt   = ws; ws += (size_t)32 * 64 * S_LEN;
  u16* Ob    = ws; ws += (size_t)4096 * 1024;

  dim3 blk256(256);
  cast_f32_bf16<<<dim3(2048), blk256, 0, stream>>>(Wq, WqBf);
  cast2_f32_bf16<<<dim3(4, 2), blk256, 0, stream>>>(Wkr, Wvr, WkrBf, WvrBf);

  transpose2_f32_bf16<<<dim3(16, 32, 2), blk256, 0, stream>>>(Wlk, Wlv, WlkT, WlvT, 2048, 1024);
  transpose_f32_bf16<<<dim3(32, 32), blk256, 0, stream>>>(Wout, WoutT, 2048, 2048);

  absorb_q<<<dim3(16, 16), blk256, 0, stream>>>(WkrBf, WqBf, Wq2T);
  absorb_o<<<dim3(16, 16), blk256, 0, stream>>>(WoutT, WvrBf, W2T);
  absorb_bq<<<dim3(4), blk256, 0, stream>>>(bq, Wkr, bq2);

  // proj: fp32 A direct-to-regs, depth-2.  768 blocks = 3/CU.
  gemm_projf<<<dim3(768), blk256, 0, stream>>>(
      queries, keys, values, Wq2T, WlkT, WlvT, bq2, blk, blv, Qp, LKb, LVb);

  transpose_lv<<<dim3(32, 32), blk256, 0, stream>>>(LVb, LVt);

  mla_attn5<<<dim3(8, 128), blk256, 0, stream>>>(Qp, LKb, LVt, Ob);

  // out: N=2048 (nxl=4, 16 x-tiles), 32 panels * 16 = 512 blocks = 2/CU
  gemm_dp<<<dim3(512), blk256, 0, stream>>>(
      Ob, W2T, bout, (float*)d_out, 2048, 1024, 4);
}

// Round 16
// 187.517 us; speedup vs baseline: 2.0318x; 2.0318x over previous
//
#include <hip/hip_runtime.h>

#define S_LEN 2048
#define NH 16

typedef unsigned short u16;
typedef __attribute__((ext_vector_type(8))) short bf16x8;
typedef __attribute__((ext_vector_type(4))) short s16x4;
typedef __attribute__((ext_vector_type(4))) unsigned short u16x4;
typedef __attribute__((ext_vector_type(4))) unsigned int u32x4;
typedef __attribute__((ext_vector_type(4))) float f32x4;

__device__ __forceinline__ u16 f2bf(float f) {
  union { float f; unsigned int i; } x; x.f = f;
  unsigned int r = x.i + 0x7FFFu + ((x.i >> 16) & 1u);
  return (u16)(r >> 16);
}
__device__ __forceinline__ unsigned pk2(float lo, float hi) {
  unsigned r;
  asm("v_cvt_pk_bf16_f32 %0, %1, %2" : "=v"(r) : "v"(lo), "v"(hi));
  return r;
}
__device__ __forceinline__ void glds16(const void* g, void* l) {
  __builtin_amdgcn_global_load_lds((const __attribute__((address_space(1))) void*)g,
                                   (__attribute__((address_space(3))) void*)l, 16, 0, 0);
}

// ---------------- cast fp32 -> bf16 (weights only) ----------------
__global__ __launch_bounds__(256) void cast_f32_bf16(const float* __restrict__ in,
                                                     u16* __restrict__ out) {
  size_t i = ((size_t)blockIdx.x * 256 + threadIdx.x) * 8;
  f32x4 a = *(const f32x4*)&in[i];
  f32x4 b = *(const f32x4*)&in[i + 4];
  u32x4 o;
  o[0] = pk2(a[0], a[1]);
  o[1] = pk2(a[2], a[3]);
  o[2] = pk2(b[0], b[1]);
  o[3] = pk2(b[2], b[3]);
  *(u32x4*)&out[i] = o;
}

__global__ __launch_bounds__(256) void cast2_f32_bf16(const float* __restrict__ i0,
                                                      const float* __restrict__ i1,
                                                      u16* __restrict__ o0,
                                                      u16* __restrict__ o1) {
  const float* in = blockIdx.y ? i1 : i0;
  u16* out = blockIdx.y ? o1 : o0;
  size_t i = ((size_t)blockIdx.x * 256 + threadIdx.x) * 8;
  f32x4 a = *(const f32x4*)&in[i];
  f32x4 b = *(const f32x4*)&in[i + 4];
  u32x4 o;
  o[0] = pk2(a[0], a[1]);
  o[1] = pk2(a[2], a[3]);
  o[2] = pk2(b[0], b[1]);
  o[3] = pk2(b[2], b[3]);
  *(u32x4*)&out[i] = o;
}

// ---------------- transpose+cast: in [K,N] fp32 -> out [N,K] bf16 ----------------
__global__ __launch_bounds__(256) void transpose2_f32_bf16(const float* __restrict__ i0,
                                                           const float* __restrict__ i1,
                                                           u16* __restrict__ o0,
                                                           u16* __restrict__ o1,
                                                           int K, int N) {
  const float* in = blockIdx.z ? i1 : i0;
  u16* out = blockIdx.z ? o1 : o0;
  __shared__ u16 tile[64][72];
  int k0 = blockIdx.y * 64, n0 = blockIdx.x * 64;
  int t = threadIdx.x;
#pragma unroll
  for (int i = 0; i < 4; ++i) {
    int idx = i * 256 + t;
    int r = idx >> 4;
    int c4 = (idx & 15) << 2;
    f32x4 v = *(const f32x4*)&in[(size_t)(k0 + r) * N + n0 + c4];
#pragma unroll
    for (int j = 0; j < 4; ++j) tile[r][c4 + j] = f2bf(v[j]);
  }
  __syncthreads();
#pragma unroll
  for (int i = 0; i < 4; ++i) {
    int idx = i * 256 + t;
    int r = idx >> 4;
    int c4 = (idx & 15) << 2;
    u16x4 v;
    v[0] = tile[c4 + 0][r];
    v[1] = tile[c4 + 1][r];
    v[2] = tile[c4 + 2][r];
    v[3] = tile[c4 + 3][r];
    *(u16x4*)&out[(size_t)(n0 + r) * K + k0 + c4] = v;
  }
}

__global__ __launch_bounds__(256) void transpose_f32_bf16(const float* __restrict__ in,
                                                          u16* __restrict__ out,
                                                          int K, int N) {
  __shared__ u16 tile[64][72];
  int k0 = blockIdx.y * 64, n0 = blockIdx.x * 64;
  int t = threadIdx.x;
#pragma unroll
  for (int i = 0; i < 4; ++i) {
    int idx = i * 256 + t;
    int r = idx >> 4;
    int c4 = (idx & 15) << 2;
    f32x4 v = *(const f32x4*)&in[(size_t)(k0 + r) * N + n0 + c4];
#pragma unroll
    for (int j = 0; j < 4; ++j) tile[r][c4 + j] = f2bf(v[j]);
  }
  __syncthreads();
#pragma unroll
  for (int i = 0; i < 4; ++i) {
    int idx = i * 256 + t;
    int r = idx >> 4;
    int c4 = (idx & 15) << 2;
    u16x4 v;
    v[0] = tile[c4 + 0][r];
    v[1] = tile[c4 + 1][r];
    v[2] = tile[c4 + 2][r];
    v[3] = tile[c4 + 3][r];
    *(u16x4*)&out[(size_t)(n0 + r) * K + k0 + c4] = v;
  }
}

// ------------- absorb_q -------------
__global__ __launch_bounds__(256) void absorb_q(const u16* __restrict__ Wkr,
                                                const u16* __restrict__ Wqb,
                                                u16* __restrict__ Wq2T) {
  int kb = blockIdx.x, h = blockIdx.y;
  int t = threadIdx.x, w = t >> 6, lane = t & 63, lq = lane & 15, hi = lane >> 4;
  int k0 = kb * 128 + w * 32;
  f32x4 acc[4][2];
#pragma unroll
  for (int i = 0; i < 4; ++i)
#pragma unroll
    for (int j = 0; j < 2; ++j) acc[i][j] = (f32x4){0.f, 0.f, 0.f, 0.f};
#pragma unroll
  for (int kk = 0; kk < 4; ++kk) {
    bf16x8 a[4], bb[2];
#pragma unroll
    for (int fld = 0; fld < 4; ++fld)
      a[fld] = *(const bf16x8*)&Wkr[(fld * 16 + lq) * 128 + kk * 32 + hi * 8];
#pragma unroll
    for (int fk = 0; fk < 2; ++fk)
      bb[fk] = *(const bf16x8*)&Wqb[(size_t)(k0 + fk * 16 + lq) * 2048 + h * 128 + kk * 32 + hi * 8];
#pragma unroll
    for (int fld = 0; fld < 4; ++fld)
#pragma unroll
      for (int fk = 0; fk < 2; ++fk)
        acc[fld][fk] = __builtin_amdgcn_mfma_f32_16x16x32_bf16(a[fld], bb[fk], acc[fld][fk], 0, 0, 0);
  }
#pragma unroll
  for (int fld = 0; fld < 4; ++fld)
#pragma unroll
    for (int fk = 0; fk < 2; ++fk)
#pragma unroll
      for (int r = 0; r < 4; ++r)
        Wq2T[(size_t)(h * 64 + fld * 16 + hi * 4 + r) * 2048 + k0 + fk * 16 + lq] =
            f2bf(acc[fld][fk][r]);
}

// ------------- absorb_o -------------
__global__ __launch_bounds__(256) void absorb_o(const u16* __restrict__ WoutT,
                                                const u16* __restrict__ Wvr,
                                                u16* __restrict__ W2T) {
  int nb = blockIdx.x, h = blockIdx.y;
  int t = threadIdx.x, w = t >> 6, lane = t & 63, lq = lane & 15, hi = lane >> 4;
  int n0 = nb * 128 + w * 32;
  f32x4 acc[2][4];
#pragma unroll
  for (int i = 0; i < 2; ++i)
#pragma unroll
    for (int j = 0; j < 4; ++j) acc[i][j] = (f32x4){0.f, 0.f, 0.f, 0.f};
#pragma unroll
  for (int kk = 0; kk < 4; ++kk) {
    bf16x8 a[2], bb[4];
#pragma unroll
    for (int fn = 0; fn < 2; ++fn)
      a[fn] = *(const bf16x8*)&WoutT[(size_t)(n0 + fn * 16 + lq) * 2048 + h * 128 + kk * 32 + hi * 8];
#pragma unroll
    for (int fld = 0; fld < 4; ++fld)
      bb[fld] = *(const bf16x8*)&Wvr[(fld * 16 + lq) * 128 + kk * 32 + hi * 8];
#pragma unroll
    for (int fn = 0; fn < 2; ++fn)
#pragma unroll
      for (int fld = 0; fld < 4; ++fld)
        acc[fn][fld] = __builtin_amdgcn_mfma_f32_16x16x32_bf16(a[fn], bb[fld], acc[fn][fld], 0, 0, 0);
  }
#pragma unroll
  for (int fn = 0; fn < 2; ++fn)
#pragma unroll
    for (int fld = 0; fld < 4; ++fld)
#pragma unroll
      for (int r = 0; r < 4; ++r)
        W2T[(size_t)(n0 + fn * 16 + hi * 4 + r) * 1024 + h * 64 + fld * 16 + lq] =
            f2bf(acc[fn][fld][r]);
}

// ------------- absorb_bq (fp32) -------------
__global__ __launch_bounds__(256) void absorb_bq(const float* __restrict__ bq,
                                                 const float* __restrict__ Wkr,
                                                 float* __restrict__ bq2) {
  int n = blockIdx.x * 256 + threadIdx.x;
  int h = n >> 6, ld = n & 63;
  float s = 0.f;
#pragma unroll 8
  for (int dk = 0; dk < 128; ++dk) s += bq[h * 128 + dk] * Wkr[ld * 128 + dk];
  bq2[n] = s;
}

// ------------- proj GEMM, fp32 A reg-staged through LDS (R13-proven, 183us config) -------------
__global__ __launch_bounds__(256, 3) void gemm_projf(const float* __restrict__ A0,
                                                     const float* __restrict__ A1,
                                                     const float* __restrict__ A2,
                                                     const u16* __restrict__ W0,
                                                     const u16* __restrict__ W1,
                                                     const u16* __restrict__ W2,
                                                     const float* __restrict__ b0,
                                                     const float* __restrict__ b1,
                                                     const float* __restrict__ b2,
                                                     u16* __restrict__ C0,
                                                     u16* __restrict__ C1,
                                                     u16* __restrict__ C2) {
  const int N = 1024, K = 2048, nxl = 3, NT = 64;
  __shared__ u16 abuf[2][128 * 32];
  __shared__ u16 bbuf[3][128 * 32];

  int Lb = blockIdx.x;
  int xcd = Lb & 7, slot = Lb >> 3;
  int panel = ((slot >> nxl) << 3) + xcd;
  int x = slot & ((1 << nxl) - 1);
  int z = panel >> 5, y = panel & 31;

  const float* A = z == 0 ? A0 : (z == 1 ? A1 : A2);
  const u16* Wt = z == 0 ? W0 : (z == 1 ? W1 : W2);
  const float* bias = z == 0 ? b0 : (z == 1 ? b1 : b2);
  u16* C = z == 0 ? C0 : (z == 1 ? C1 : C2);

  int m0 = y * 128, n0 = x * 128;
  int t = threadIdx.x;
  int lane = t & 63, lq = lane & 15, hi = lane >> 4;
  int w = t >> 6, wm = w >> 1, wn = w & 1;

  struct a16 { f32x4 lo, hi; };
  a16 areg[2][2];

  f32x4 acc[4][4];
#pragma unroll
  for (int im = 0; im < 4; ++im)
#pragma unroll
    for (int fn = 0; fn < 4; ++fn) acc[im][fn] = (f32x4){0.f, 0.f, 0.f, 0.f};

#define LOADA(SLOT, KT)                                                              \
  do {                                                                               \
    int kb_ = (KT) * 32;                                                             \
    _Pragma("unroll") for (int i = 0; i < 2; ++i) {                                  \
      int idx = i * 256 + t, row = idx >> 2, c = idx & 3;                            \
      const float* ap = &A[(size_t)(m0 + row) * K + kb_ + ((c ^ ((row >> 1) & 3)) << 3)]; \
      areg[SLOT][i].lo = *(const f32x4*)ap;                                          \
      areg[SLOT][i].hi = *(const f32x4*)(ap + 4);                                    \
    }                                                                                \
  } while (0)

#define WRITEA(SLOT)                                                                 \
  do {                                                                               \
    _Pragma("unroll") for (int i = 0; i < 2; ++i) {                                  \
      u32x4 o;                                                                       \
      o[0] = pk2(areg[SLOT][i].lo[0], areg[SLOT][i].lo[1]);                          \
      o[1] = pk2(areg[SLOT][i].lo[2], areg[SLOT][i].lo[3]);                          \
      o[2] = pk2(areg[SLOT][i].hi[0], areg[SLOT][i].hi[1]);                          \
      o[3] = pk2(areg[SLOT][i].hi[2], areg[SLOT][i].hi[3]);                          \
      *(u32x4*)&abuf[SLOT][(i * 256 + t) * 8] = o;                                   \
    }                                                                                \
  } while (0)

#define STAGEB(KT)                                                                   \
  do {                                                                               \
    int kb_ = (KT) * 32;                                                             \
    u16* lB_ = &bbuf[(KT) % 3][0];                                                   \
    _Pragma("unroll") for (int i = 0; i < 2; ++i) {                                  \
      int idx = i * 256 + t, row = idx >> 2, c = idx & 3;                            \
      glds16(&Wt[(size_t)(n0 + row) * K + kb_ + ((c ^ ((row >> 1) & 3)) << 3)], lB_ + idx * 8); \
    }                                                                                \
  } while (0)

#define COMPUTE(PAR, TT)                                                             \
  do {                                                                               \
    const u16* lB_ = &bbuf[(TT) % 3][0];                                             \
    bf16x8 bf[4];                                                                    \
    _Pragma("unroll") for (int fn = 0; fn < 4; ++fn) {                               \
      int row = wn * 64 + fn * 16 + lq;                                              \
      bf[fn] = *(const bf16x8*)&lB_[row * 32 + ((hi ^ ((row >> 1) & 3)) << 3)];      \
    }                                                                                \
    __builtin_amdgcn_s_setprio(1);                                                   \
    _Pragma("unroll") for (int im = 0; im < 4; ++im) {                               \
      int row = wm * 64 + im * 16 + lq;                                              \
      bf16x8 af = *(const bf16x8*)&abuf[PAR][row * 32 + ((hi ^ ((row >> 1) & 3)) << 3)]; \
      _Pragma("unroll") for (int fn = 0; fn < 4; ++fn)                               \
        acc[im][fn] = __builtin_amdgcn_mfma_f32_16x16x32_bf16(af, bf[fn], acc[im][fn], 0, 0, 0); \
    }                                                                                \
    __builtin_amdgcn_s_setprio(0);                                                   \
  } while (0)

#define PSTEP(TT, PAR)                                                               \
  do {                                                                               \
    if ((TT) + 2 < NT) {                                                             \
      LOADA(PAR, (TT) + 2);                                                          \
      STAGEB((TT) + 2);                                                              \
    }                                                                                \
    COMPUTE(PAR, TT);                                                                \
    if ((TT) + 1 < NT) WRITEA(PAR ^ 1);                                              \
    if ((TT) + 2 < NT)                                                               \
      asm volatile("s_waitcnt vmcnt(6)" ::: "memory");                               \
    else                                                                             \
      asm volatile("s_waitcnt vmcnt(0)" ::: "memory");                               \
    asm volatile("s_waitcnt lgkmcnt(0)" ::: "memory");                               \
    __builtin_amdgcn_s_barrier();                                                    \
    __builtin_amdgcn_sched_barrier(0);                                               \
  } while (0)

  LOADA(0, 0);
  STAGEB(0);
  LOADA(1, 1);
  STAGEB(1);
  asm volatile("s_waitcnt vmcnt(8)" ::: "memory");
  WRITEA(0);
  asm volatile("s_waitcnt vmcnt(6)" ::: "memory");
  asm volatile("s_waitcnt lgkmcnt(0)" ::: "memory");
  __builtin_amdgcn_s_barrier();
  __builtin_amdgcn_sched_barrier(0);

  for (int tt = 0; tt < NT; tt += 2) {
    PSTEP(tt, 0);
    PSTEP(tt + 1, 1);
  }

#pragma unroll
  for (int im = 0; im < 4; ++im)
#pragma unroll
    for (int fn = 0; fn < 4; ++fn) {
      int col = n0 + wn * 64 + fn * 16 + lq;
      float bv = bias[col];
      int rbase = m0 + wm * 64 + im * 16 + hi * 4;
#pragma unroll
      for (int r = 0; r < 4; ++r)
        C[(size_t)(rbase + r) * N + col] = f2bf(acc[im][fn][r] + bv);
    }
#undef LOADA
#undef WRITEA
#undef STAGEB
#undef COMPUTE
#undef PSTEP
}

// ------------- out-proj GEMM (bf16 A, R10-proven): BM=BN=128, BK=32, 3 bufs, vmcnt(4) -------------
__global__ __launch_bounds__(256, 3) void gemm_dp(const u16* __restrict__ A,
                                                  const u16* __restrict__ Wt,
                                                  const float* __restrict__ bias,
                                                  float* __restrict__ Cv,
                                                  int N, int K, int nxl) {
  __shared__ u16 ldsA[3][128 * 32];
  __shared__ u16 ldsB[3][128 * 32];

  int Lb = blockIdx.x;
  int xcd = Lb & 7, slot = Lb >> 3;
  int panel = ((slot >> nxl) << 3) + xcd;
  int x = slot & ((1 << nxl) - 1);
  int y = panel & 31;

  int m0 = y * 128, n0 = x * 128;
  int t = threadIdx.x;
  int lane = t & 63, lq = lane & 15, hi = lane >> 4;
  int w = t >> 6, wm = w >> 1, wn = w & 1;
  int NT = K >> 5;

  auto stage = [&](int q, int kt) {
    u16* lA = &ldsA[q][0];
    u16* lB = &ldsB[q][0];
    int kb = kt * 32;
#pragma unroll
    for (int i = 0; i < 2; ++i) {
      int idx = i * 256 + t;
      int row = idx >> 2, c = idx & 3;
      glds16(&A[(size_t)(m0 + row) * K + kb + ((c ^ ((row >> 1) & 3)) << 3)], lA + idx * 8);
    }
#pragma unroll
    for (int i = 0; i < 2; ++i) {
      int idx = i * 256 + t;
      int row = idx >> 2, c = idx & 3;
      glds16(&Wt[(size_t)(n0 + row) * K + kb + ((c ^ ((row >> 1) & 3)) << 3)], lB + idx * 8);
    }
  };

  f32x4 acc[4][4];
#pragma unroll
  for (int im = 0; im < 4; ++im)
#pragma unroll
    for (int fn = 0; fn < 4; ++fn) acc[im][fn] = (f32x4){0.f, 0.f, 0.f, 0.f};

  stage(0, 0);
  stage(1, 1);
  asm volatile("s_waitcnt vmcnt(4)" ::: "memory");
  __builtin_amdgcn_s_barrier();

  for (int tt = 0; tt < NT; ++tt) {
    int q = tt % 3;
    if (tt + 2 < NT) stage((tt + 2) % 3, tt + 2);
    const u16* lA = &ldsA[q][0];
    const u16* lB = &ldsB[q][0];
    bf16x8 bf[4];
#pragma unroll
    for (int fn = 0; fn < 4; ++fn) {
      int row = wn * 64 + fn * 16 + lq;
      bf[fn] = *(const bf16x8*)&lB[row * 32 + ((hi ^ ((row >> 1) & 3)) << 3)];
    }
    __builtin_amdgcn_s_setprio(1);
#pragma unroll
    for (int im = 0; im < 4; ++im) {
      int row = wm * 64 + im * 16 + lq;
      bf16x8 af = *(const bf16x8*)&lA[row * 32 + ((hi ^ ((row >> 1) & 3)) << 3)];
#pragma unroll
      for (int fn = 0; fn < 4; ++fn)
        acc[im][fn] = __builtin_amdgcn_mfma_f32_16x16x32_bf16(af, bf[fn], acc[im][fn], 0, 0, 0);
    }
    __builtin_amdgcn_s_setprio(0);
    if (tt + 2 < NT)
      asm volatile("s_waitcnt vmcnt(4)" ::: "memory");
    else
      asm volatile("s_waitcnt vmcnt(0)" ::: "memory");
    __builtin_amdgcn_s_barrier();
  }

#pragma unroll
  for (int im = 0; im < 4; ++im)
#pragma unroll
    for (int fn = 0; fn < 4; ++fn) {
      int col = n0 + wn * 64 + fn * 16 + lq;
      float bv = bias[col];
      int rbase = m0 + wm * 64 + im * 16 + hi * 4;
#pragma unroll
      for (int r = 0; r < 4; ++r)
        Cv[(size_t)(rbase + r) * N + col] = acc[im][fn][r] + bv;
    }
}

// ------------- transpose_lv: LV[b][s][h*64+ld] -> LVt[bh][ld][s], sigma-permuted per 32-s -------------
__global__ __launch_bounds__(256) void transpose_lv(const u16* __restrict__ LV,
                                                    u16* __restrict__ out) {
  __shared__ u16 tile[64 * 72];
  int st = blockIdx.x, bh = blockIdx.y;
  int b = bh >> 4, h = bh & 15;
  int t = threadIdx.x;
  int s0 = st * 64;
#pragma unroll
  for (int i = 0; i < 2; ++i) {
    int idx = i * 256 + t;
    int sr = idx >> 3, c8 = idx & 7;
    bf16x8 v = *(const bf16x8*)&LV[(size_t)(b * S_LEN + s0 + sr) * 1024 + h * 64 + c8 * 8];
    int pos = (sr & 32) + ((sr & 12) << 1) + ((sr & 16) >> 2) + (sr & 3);
#pragma unroll
    for (int j = 0; j < 8; ++j) tile[(c8 * 8 + j) * 72 + pos] = (u16)v[j];
  }
  __syncthreads();
  u16* ob = out + (size_t)bh * 64 * S_LEN;
#pragma unroll
  for (int i = 0; i < 2; ++i) {
    int idx = i * 256 + t;
    int ld = idx >> 3, c8 = idx & 7;
    bf16x8 v = *(const bf16x8*)&tile[ld * 72 + c8 * 8];
    *(bf16x8*)&ob[(size_t)ld * S_LEN + s0 + c8 * 8] = v;
  }
}

// ------------- latent flash attention: QBLK=64, 3-buffer counted-vmcnt pipeline (48KB LDS) -------------
__global__ __launch_bounds__(256) void mla_attn6(const u16* __restrict__ Qp,
                                                 const u16* __restrict__ LK,
                                                 const u16* __restrict__ LVt,
                                                 u16* __restrict__ O) {
  __shared__ u16 smem[24576];  // lK: 3 x 4096 @ 0; lV: 3 x 4096 @ 12288
  int Lb = blockIdx.x + blockIdx.y * 8;
  int half = Lb >> 9;
  int i0 = Lb & 511;
  int xcd = i0 & 7, ii = i0 >> 3;
  int bh = xcd * 4 + (ii & 3);
  int pr = ii >> 2;
  int qsup = half ? (31 - pr) : pr;
  int b = bh >> 4, h = bh & 15;
  int t = threadIdx.x, w = t >> 6, lane = t & 63, lq = lane & 15, hi = lane >> 4;
  int lq7 = lq & 7;

  const u16* Kb = LK + (size_t)b * S_LEN * 1024 + h * 64;
  const u16* Vb = LVt + (size_t)bh * 64 * S_LEN;
  const float scale = 0.08838834764831845f;

  auto stage = [&](int buf, int k0) {
    u16* lK = smem + buf * 4096;
    u16* lV = smem + 12288 + buf * 4096;
#pragma unroll
    for (int i = 0; i < 2; ++i) {
      int idx = i * 256 + t;
      int row = idx >> 3, c8 = idx & 7;
      glds16(Kb + (size_t)(k0 + row) * 1024 + ((c8 ^ (row & 7)) << 3), lK + idx * 8);
    }
#pragma unroll
    for (int i = 0; i < 2; ++i) {
      int idx = i * 256 + t;
      int row = idx >> 3, c8 = idx & 7;
      glds16(Vb + (size_t)row * S_LEN + k0 + ((c8 ^ (row & 7)) << 3), lV + idx * 8);
    }
  };

  int qb = qsup * 64;
  int nt = qsup + 1;
  int q0 = qb + w * 16;
  int kmax = q0 + 16;

  bf16x8 qf[2];
  {
    const u16* Qrow = Qp + (size_t)(b * S_LEN + q0 + lq) * 1024 + h * 64;
    qf[0] = *(const bf16x8*)&Qrow[hi * 8];
    qf[1] = *(const bf16x8*)&Qrow[32 + hi * 8];
  }

  f32x4 acc[4];
#pragma unroll
  for (int f = 0; f < 4; ++f) acc[f] = (f32x4){0.f, 0.f, 0.f, 0.f};
  float m = -1e30f, l = 0.f;

  // prologue: stage tiles 0 and 1 (tile-1 addresses are in-bounds even when unused)
  stage(0, 0);
  stage(1, 64);
  asm volatile("s_waitcnt vmcnt(4)" ::: "memory");  // tile 0 landed; tile 1 in flight
  __builtin_amdgcn_s_barrier();

  for (int tt = 0; tt < nt; ++tt) {
    if (tt + 2 < nt) stage((tt + 2) % 3, (tt + 2) * 64);
    int k0 = tt * 64;
    if (k0 < kmax) {
      const u16* lK = smem + (tt % 3) * 4096;
      const u16* lV = smem + 12288 + (tt % 3) * 4096;
      f32x4 sc[4];
#pragma unroll
      for (int kf = 0; kf < 4; ++kf) sc[kf] = (f32x4){0.f, 0.f, 0.f, 0.f};
      __builtin_amdgcn_s_setprio(1);
#pragma unroll
      for (int kf = 0; kf < 4; ++kf) {
        const u16* kr = lK + (kf * 16 + lq) * 64;
#pragma unroll
        for (int d0 = 0; d0 < 2; ++d0) {
          bf16x8 af = *(const bf16x8*)&kr[(((d0 << 2) + hi) ^ lq7) << 3];
          sc[kf] = __builtin_amdgcn_mfma_f32_16x16x32_bf16(af, qf[d0], sc[kf], 0, 0, 0);
        }
      }
      __builtin_amdgcn_s_setprio(0);
      int q = q0 + lq;
      float sv[16];
#pragma unroll
      for (int kf = 0; kf < 4; ++kf)
#pragma unroll
        for (int r = 0; r < 4; ++r) sv[kf * 4 + r] = sc[kf][r] * scale;
      if (k0 + 63 > q0) {
#pragma unroll
        for (int kf = 0; kf < 4; ++kf)
#pragma unroll
          for (int r = 0; r < 4; ++r)
            if (k0 + kf * 16 + hi * 4 + r > q) sv[kf * 4 + r] = -1e30f;
      }
      float tm = sv[0];
#pragma unroll
      for (int j = 1; j < 16; ++j) tm = fmaxf(tm, sv[j]);
      tm = fmaxf(tm, __shfl_xor(tm, 16));
      tm = fmaxf(tm, __shfl_xor(tm, 32));
      float p[16], ps = 0.f;
      if (__all(tm <= m + 8.f)) {
#pragma unroll
        for (int j = 0; j < 16; ++j) { p[j] = __expf(sv[j] - m); ps += p[j]; }
        ps += __shfl_xor(ps, 16);
        ps += __shfl_xor(ps, 32);
        l += ps;
      } else {
        float mnew = fmaxf(m, tm);
        float alpha = __expf(m - mnew);
#pragma unroll
        for (int j = 0; j < 16; ++j) { p[j] = __expf(sv[j] - mnew); ps += p[j]; }
        ps += __shfl_xor(ps, 16);
        ps += __shfl_xor(ps, 32);
        l = l * alpha + ps;
        m = mnew;
#pragma unroll
        for (int f = 0; f < 4; ++f) {
          acc[f][0] *= alpha; acc[f][1] *= alpha;
          acc[f][2] *= alpha; acc[f][3] *= alpha;
        }
      }
      bf16x8 pb[2];
#pragma unroll
      for (int ks = 0; ks < 2; ++ks) {
        union { u32x4 u; bf16x8 v; } pu;
#pragma unroll
        for (int wd = 0; wd < 4; ++wd) pu.u[wd] = pk2(p[ks * 8 + 2 * wd], p[ks * 8 + 2 * wd + 1]);
        pb[ks] = pu.v;
      }
      __builtin_amdgcn_s_setprio(1);
#pragma unroll
      for (int f = 0; f < 4; ++f) {
        const u16* vr = lV + (f * 16 + lq) * 64;
#pragma unroll
        for (int ks = 0; ks < 2; ++ks) {
          bf16x8 va = *(const bf16x8*)&vr[(((ks << 2) + hi) ^ lq7) << 3];
          acc[f] = __builtin_amdgcn_mfma_f32_16x16x32_bf16(va, pb[ks], acc[f], 0, 0, 0);
        }
      }
      __builtin_amdgcn_s_setprio(0);
    }
    // counted wait: tile t+1 must be resident for next phase; tile t+2 (4 loads) stays in flight
    if (tt + 2 < nt)
      asm volatile("s_waitcnt vmcnt(4)" ::: "memory");
    else
      asm volatile("s_waitcnt vmcnt(0)" ::: "memory");
    __builtin_amdgcn_s_barrier();
  }
  {
    float inv = 1.f / l;
    int qloc = w * 16 + lq;
#pragma unroll
    for (int f = 0; f < 4; ++f)
#pragma unroll
      for (int r = 0; r < 4; ++r) {
        int col = f * 16 + hi * 4 + r;
        smem[qloc * 64 + (((col >> 3) ^ lq7) << 3) + (col & 7)] = f2bf(acc[f][r] * inv);
      }
  }
  __syncthreads();
#pragma unroll
  for (int i = 0; i < 2; ++i) {
    int cid = i * 256 + t;
    int q = cid >> 3, ch = cid & 7;
    bf16x8 v = *(const bf16x8*)&smem[q * 64 + ((ch ^ (q & 7)) << 3)];
    *(bf16x8*)&O[(size_t)(b * S_LEN + qb + q) * 1024 + h * 64 + (ch << 3)] = v;
  }
}

extern "C" void kernel_launch(void* const* d_in, const int* in_sizes, int n_in,
                              void* d_out, int out_size, void* d_ws, size_t ws_size,
                              hipStream_t stream) {
  const float* queries = (const float*)d_in[0];
  const float* keys    = (const float*)d_in[1];
  const float* values  = (const float*)d_in[2];
  const float* Wq      = (const float*)d_in[3];
  const float* bq      = (const float*)d_in[4];
  const float* Wlk     = (const float*)d_in[5];
  const float* blk     = (const float*)d_in[6];
  const float* Wlv     = (const float*)d_in[7];
  const float* blv     = (const float*)d_in[8];
  const float* Wkr     = (const float*)d_in[9];
  const float* Wvr     = (const float*)d_in[10];
  const float* Wout    = (const float*)d_in[11];
  const float* bout    = (const float*)d_in[12];

  u16* ws = (u16*)d_ws;
  u16* WqBf  = ws; ws += (size_t)2048 * 2048;
  u16* WkrBf = ws; ws += 64 * 128;
  u16* WvrBf = ws; ws += 64 * 128;
  u16* WoutT = ws; ws += (size_t)2048 * 2048;
  u16* WlkT  = ws; ws += (size_t)1024 * 2048;
  u16* WlvT  = ws; ws += (size_t)1024 * 2048;
  u16* Wq2T  = ws; ws += (size_t)1024 * 2048;
  u16* W2T   = ws; ws += (size_t)2048 * 1024;
  float* bq2 = (float*)ws; ws += 2048;
  u16* Qp    = ws; ws += (size_t)4096 * 1024;
  u16* LKb   = ws; ws += (size_t)4096 * 1024;
  u16* LVb   = ws; ws += (size_t)4096 * 1024;
  u16* LVt   = ws; ws += (size_t)32 * 64 * S_LEN;
  u16* Ob    = ws; ws += (size_t)4096 * 1024;

  dim3 blk256(256);
  cast_f32_bf16<<<dim3(2048), blk256, 0, stream>>>(Wq, WqBf);
  cast2_f32_bf16<<<dim3(4, 2), blk256, 0, stream>>>(Wkr, Wvr, WkrBf, WvrBf);

  transpose2_f32_bf16<<<dim3(16, 32, 2), blk256, 0, stream>>>(Wlk, Wlv, WlkT, WlvT, 2048, 1024);
  transpose_f32_bf16<<<dim3(32, 32), blk256, 0, stream>>>(Wout, WoutT, 2048, 2048);

  absorb_q<<<dim3(16, 16), blk256, 0, stream>>>(WkrBf, WqBf, Wq2T);
  absorb_o<<<dim3(16, 16), blk256, 0, stream>>>(WoutT, WvrBf, W2T);
  absorb_bq<<<dim3(4), blk256, 0, stream>>>(bq, Wkr, bq2);

  // proj: fp32 A LDS-staged (R13 config).  768 blocks = 3/CU.
  gemm_projf<<<dim3(768), blk256, 0, stream>>>(
      queries, keys, values, Wq2T, WlkT, WlvT, bq2, blk, blv, Qp, LKb, LVb);

  transpose_lv<<<dim3(32, 32), blk256, 0, stream>>>(LVb, LVt);

  mla_attn6<<<dim3(8, 128), blk256, 0, stream>>>(Qp, LKb, LVt, Ob);

  // out: N=2048 (nxl=4, 16 x-tiles), 32 panels * 16 = 512 blocks = 2/CU
  gemm_dp<<<dim3(512), blk256, 0, stream>>>(
      Ob, W2T, bout, (float*)d_out, 2048, 1024, 4);
}

// Round 17
// 182.411 us; speedup vs baseline: 2.0887x; 1.0280x over previous
//
#include <hip/hip_runtime.h>

#define S_LEN 2048
#define NH 16

typedef unsigned short u16;
typedef __attribute__((ext_vector_type(8))) short bf16x8;
typedef __attribute__((ext_vector_type(4))) short s16x4;
typedef __attribute__((ext_vector_type(4))) unsigned short u16x4;
typedef __attribute__((ext_vector_type(4))) unsigned int u32x4;
typedef __attribute__((ext_vector_type(4))) float f32x4;

__device__ __forceinline__ u16 f2bf(float f) {
  union { float f; unsigned int i; } x; x.f = f;
  unsigned int r = x.i + 0x7FFFu + ((x.i >> 16) & 1u);
  return (u16)(r >> 16);
}
__device__ __forceinline__ unsigned pk2(float lo, float hi) {
  unsigned r;
  asm("v_cvt_pk_bf16_f32 %0, %1, %2" : "=v"(r) : "v"(lo), "v"(hi));
  return r;
}
__device__ __forceinline__ void glds16(const void* g, void* l) {
  __builtin_amdgcn_global_load_lds((const __attribute__((address_space(1))) void*)g,
                                   (__attribute__((address_space(3))) void*)l, 16, 0, 0);
}

// ---------------- cast fp32 -> bf16 (weights only) ----------------
__global__ __launch_bounds__(256) void cast_f32_bf16(const float* __restrict__ in,
                                                     u16* __restrict__ out) {
  size_t i = ((size_t)blockIdx.x * 256 + threadIdx.x) * 8;
  f32x4 a = *(const f32x4*)&in[i];
  f32x4 b = *(const f32x4*)&in[i + 4];
  u32x4 o;
  o[0] = pk2(a[0], a[1]);
  o[1] = pk2(a[2], a[3]);
  o[2] = pk2(b[0], b[1]);
  o[3] = pk2(b[2], b[3]);
  *(u32x4*)&out[i] = o;
}

__global__ __launch_bounds__(256) void cast2_f32_bf16(const float* __restrict__ i0,
                                                      const float* __restrict__ i1,
                                                      u16* __restrict__ o0,
                                                      u16* __restrict__ o1) {
  const float* in = blockIdx.y ? i1 : i0;
  u16* out = blockIdx.y ? o1 : o0;
  size_t i = ((size_t)blockIdx.x * 256 + threadIdx.x) * 8;
  f32x4 a = *(const f32x4*)&in[i];
  f32x4 b = *(const f32x4*)&in[i + 4];
  u32x4 o;
  o[0] = pk2(a[0], a[1]);
  o[1] = pk2(a[2], a[3]);
  o[2] = pk2(b[0], b[1]);
  o[3] = pk2(b[2], b[3]);
  *(u32x4*)&out[i] = o;
}

// ---------------- transpose+cast: in [K,N] fp32 -> out [N,K] bf16 ----------------
__global__ __launch_bounds__(256) void transpose2_f32_bf16(const float* __restrict__ i0,
                                                           const float* __restrict__ i1,
                                                           u16* __restrict__ o0,
                                                           u16* __restrict__ o1,
                                                           int K, int N) {
  const float* in = blockIdx.z ? i1 : i0;
  u16* out = blockIdx.z ? o1 : o0;
  __shared__ u16 tile[64][72];
  int k0 = blockIdx.y * 64, n0 = blockIdx.x * 64;
  int t = threadIdx.x;
#pragma unroll
  for (int i = 0; i < 4; ++i) {
    int idx = i * 256 + t;
    int r = idx >> 4;
    int c4 = (idx & 15) << 2;
    f32x4 v = *(const f32x4*)&in[(size_t)(k0 + r) * N + n0 + c4];
#pragma unroll
    for (int j = 0; j < 4; ++j) tile[r][c4 + j] = f2bf(v[j]);
  }
  __syncthreads();
#pragma unroll
  for (int i = 0; i < 4; ++i) {
    int idx = i * 256 + t;
    int r = idx >> 4;
    int c4 = (idx & 15) << 2;
    u16x4 v;
    v[0] = tile[c4 + 0][r];
    v[1] = tile[c4 + 1][r];
    v[2] = tile[c4 + 2][r];
    v[3] = tile[c4 + 3][r];
    *(u16x4*)&out[(size_t)(n0 + r) * K + k0 + c4] = v;
  }
}

__global__ __launch_bounds__(256) void transpose_f32_bf16(const float* __restrict__ in,
                                                          u16* __restrict__ out,
                                                          int K, int N) {
  __shared__ u16 tile[64][72];
  int k0 = blockIdx.y * 64, n0 = blockIdx.x * 64;
  int t = threadIdx.x;
#pragma unroll
  for (int i = 0; i < 4; ++i) {
    int idx = i * 256 + t;
    int r = idx >> 4;
    int c4 = (idx & 15) << 2;
    f32x4 v = *(const f32x4*)&in[(size_t)(k0 + r) * N + n0 + c4];
#pragma unroll
    for (int j = 0; j < 4; ++j) tile[r][c4 + j] = f2bf(v[j]);
  }
  __syncthreads();
#pragma unroll
  for (int i = 0; i < 4; ++i) {
    int idx = i * 256 + t;
    int r = idx >> 4;
    int c4 = (idx & 15) << 2;
    u16x4 v;
    v[0] = tile[c4 + 0][r];
    v[1] = tile[c4 + 1][r];
    v[2] = tile[c4 + 2][r];
    v[3] = tile[c4 + 3][r];
    *(u16x4*)&out[(size_t)(n0 + r) * K + k0 + c4] = v;
  }
}

// ------------- absorb_q -------------
__global__ __launch_bounds__(256) void absorb_q(const u16* __restrict__ Wkr,
                                                const u16* __restrict__ Wqb,
                                                u16* __restrict__ Wq2T) {
  int kb = blockIdx.x, h = blockIdx.y;
  int t = threadIdx.x, w = t >> 6, lane = t & 63, lq = lane & 15, hi = lane >> 4;
  int k0 = kb * 128 + w * 32;
  f32x4 acc[4][2];
#pragma unroll
  for (int i = 0; i < 4; ++i)
#pragma unroll
    for (int j = 0; j < 2; ++j) acc[i][j] = (f32x4){0.f, 0.f, 0.f, 0.f};
#pragma unroll
  for (int kk = 0; kk < 4; ++kk) {
    bf16x8 a[4], bb[2];
#pragma unroll
    for (int fld = 0; fld < 4; ++fld)
      a[fld] = *(const bf16x8*)&Wkr[(fld * 16 + lq) * 128 + kk * 32 + hi * 8];
#pragma unroll
    for (int fk = 0; fk < 2; ++fk)
      bb[fk] = *(const bf16x8*)&Wqb[(size_t)(k0 + fk * 16 + lq) * 2048 + h * 128 + kk * 32 + hi * 8];
#pragma unroll
    for (int fld = 0; fld < 4; ++fld)
#pragma unroll
      for (int fk = 0; fk < 2; ++fk)
        acc[fld][fk] = __builtin_amdgcn_mfma_f32_16x16x32_bf16(a[fld], bb[fk], acc[fld][fk], 0, 0, 0);
  }
#pragma unroll
  for (int fld = 0; fld < 4; ++fld)
#pragma unroll
    for (int fk = 0; fk < 2; ++fk)
#pragma unroll
      for (int r = 0; r < 4; ++r)
        Wq2T[(size_t)(h * 64 + fld * 16 + hi * 4 + r) * 2048 + k0 + fk * 16 + lq] =
            f2bf(acc[fld][fk][r]);
}

// ------------- absorb_o -------------
__global__ __launch_bounds__(256) void absorb_o(const u16* __restrict__ WoutT,
                                                const u16* __restrict__ Wvr,
                                                u16* __restrict__ W2T) {
  int nb = blockIdx.x, h = blockIdx.y;
  int t = threadIdx.x, w = t >> 6, lane = t & 63, lq = lane & 15, hi = lane >> 4;
  int n0 = nb * 128 + w * 32;
  f32x4 acc[2][4];
#pragma unroll
  for (int i = 0; i < 2; ++i)
#pragma unroll
    for (int j = 0; j < 4; ++j) acc[i][j] = (f32x4){0.f, 0.f, 0.f, 0.f};
#pragma unroll
  for (int kk = 0; kk < 4; ++kk) {
    bf16x8 a[2], bb[4];
#pragma unroll
    for (int fn = 0; fn < 2; ++fn)
      a[fn] = *(const bf16x8*)&WoutT[(size_t)(n0 + fn * 16 + lq) * 2048 + h * 128 + kk * 32 + hi * 8];
#pragma unroll
    for (int fld = 0; fld < 4; ++fld)
      bb[fld] = *(const bf16x8*)&Wvr[(fld * 16 + lq) * 128 + kk * 32 + hi * 8];
#pragma unroll
    for (int fn = 0; fn < 2; ++fn)
#pragma unroll
      for (int fld = 0; fld < 4; ++fld)
        acc[fn][fld] = __builtin_amdgcn_mfma_f32_16x16x32_bf16(a[fn], bb[fld], acc[fn][fld], 0, 0, 0);
  }
#pragma unroll
  for (int fn = 0; fn < 2; ++fn)
#pragma unroll
    for (int fld = 0; fld < 4; ++fld)
#pragma unroll
      for (int r = 0; r < 4; ++r)
        W2T[(size_t)(n0 + fn * 16 + hi * 4 + r) * 1024 + h * 64 + fld * 16 + lq] =
            f2bf(acc[fn][fld][r]);
}

// ------------- absorb_bq (fp32) -------------
__global__ __launch_bounds__(256) void absorb_bq(const float* __restrict__ bq,
                                                 const float* __restrict__ Wkr,
                                                 float* __restrict__ bq2) {
  int n = blockIdx.x * 256 + threadIdx.x;
  int h = n >> 6, ld = n & 63;
  float s = 0.f;
#pragma unroll 8
  for (int dk = 0; dk < 128; ++dk) s += bq[h * 128 + dk] * Wkr[ld * 128 + dk];
  bq2[n] = s;
}

// ------------- proj GEMM, fp32 A reg-staged through LDS (R12 schedule, 113-115us measured) -------------
__global__ __launch_bounds__(256, 3) void gemm_projf(const float* __restrict__ A0,
                                                     const float* __restrict__ A1,
                                                     const float* __restrict__ A2,
                                                     const u16* __restrict__ W0,
                                                     const u16* __restrict__ W1,
                                                     const u16* __restrict__ W2,
                                                     const float* __restrict__ b0,
                                                     const float* __restrict__ b1,
                                                     const float* __restrict__ b2,
                                                     u16* __restrict__ C0,
                                                     u16* __restrict__ C1,
                                                     u16* __restrict__ C2) {
  const int N = 1024, K = 2048, nxl = 3, NT = 64;
  __shared__ u16 abuf[2][128 * 32];
  __shared__ u16 bbuf[3][128 * 32];

  int Lb = blockIdx.x;
  int xcd = Lb & 7, slot = Lb >> 3;
  int panel = ((slot >> nxl) << 3) + xcd;
  int x = slot & ((1 << nxl) - 1);
  int z = panel >> 5, y = panel & 31;

  const float* A = z == 0 ? A0 : (z == 1 ? A1 : A2);
  const u16* Wt = z == 0 ? W0 : (z == 1 ? W1 : W2);
  const float* bias = z == 0 ? b0 : (z == 1 ? b1 : b2);
  u16* C = z == 0 ? C0 : (z == 1 ? C1 : C2);

  int m0 = y * 128, n0 = x * 128;
  int t = threadIdx.x;
  int lane = t & 63, lq = lane & 15, hi = lane >> 4;
  int w = t >> 6, wm = w >> 1, wn = w & 1;

  struct a16 { f32x4 lo, hi; };
  a16 areg[2][2];  // [slot][i] -- compile-time indices

  f32x4 acc[4][4];
#pragma unroll
  for (int im = 0; im < 4; ++im)
#pragma unroll
    for (int fn = 0; fn < 4; ++fn) acc[im][fn] = (f32x4){0.f, 0.f, 0.f, 0.f};

#define LOADA(SLOT, KT)                                                              \
  do {                                                                               \
    int kb_ = (KT) * 32;                                                             \
    _Pragma("unroll") for (int i = 0; i < 2; ++i) {                                  \
      int idx = i * 256 + t, row = idx >> 2, c = idx & 3;                            \
      const float* ap = &A[(size_t)(m0 + row) * K + kb_ + ((c ^ ((row >> 1) & 3)) << 3)]; \
      areg[SLOT][i].lo = *(const f32x4*)ap;                                          \
      areg[SLOT][i].hi = *(const f32x4*)(ap + 4);                                    \
    }                                                                                \
  } while (0)

#define WRITEA(SLOT)                                                                 \
  do {                                                                               \
    _Pragma("unroll") for (int i = 0; i < 2; ++i) {                                  \
      u32x4 o;                                                                       \
      o[0] = pk2(areg[SLOT][i].lo[0], areg[SLOT][i].lo[1]);                          \
      o[1] = pk2(areg[SLOT][i].lo[2], areg[SLOT][i].lo[3]);                          \
      o[2] = pk2(areg[SLOT][i].hi[0], areg[SLOT][i].hi[1]);                          \
      o[3] = pk2(areg[SLOT][i].hi[2], areg[SLOT][i].hi[3]);                          \
      *(u32x4*)&abuf[SLOT][(i * 256 + t) * 8] = o;                                   \
    }                                                                                \
  } while (0)

#define STAGEB(KT)                                                                   \
  do {                                                                               \
    int kb_ = (KT) * 32;                                                             \
    u16* lB_ = &bbuf[(KT) % 3][0];                                                   \
    _Pragma("unroll") for (int i = 0; i < 2; ++i) {                                  \
      int idx = i * 256 + t, row = idx >> 2, c = idx & 3;                            \
      glds16(&Wt[(size_t)(n0 + row) * K + kb_ + ((c ^ ((row >> 1) & 3)) << 3)], lB_ + idx * 8); \
    }                                                                                \
  } while (0)

#define COMPUTE(PAR, TT)                                                             \
  do {                                                                               \
    const u16* lB_ = &bbuf[(TT) % 3][0];                                             \
    bf16x8 bf[4];                                                                    \
    _Pragma("unroll") for (int fn = 0; fn < 4; ++fn) {                               \
      int row = wn * 64 + fn * 16 + lq;                                              \
      bf[fn] = *(const bf16x8*)&lB_[row * 32 + ((hi ^ ((row >> 1) & 3)) << 3)];      \
    }                                                                                \
    __builtin_amdgcn_s_setprio(1);                                                   \
    _Pragma("unroll") for (int im = 0; im < 4; ++im) {                               \
      int row = wm * 64 + im * 16 + lq;                                              \
      bf16x8 af = *(const bf16x8*)&abuf[PAR][row * 32 + ((hi ^ ((row >> 1) & 3)) << 3)]; \
      _Pragma("unroll") for (int fn = 0; fn < 4; ++fn)                               \
        acc[im][fn] = __builtin_amdgcn_mfma_f32_16x16x32_bf16(af, bf[fn], acc[im][fn], 0, 0, 0); \
    }                                                                                \
    __builtin_amdgcn_s_setprio(0);                                                   \
  } while (0)

#define PSTEP(TT, PAR)                                                               \
  do {                                                                               \
    if ((TT) + 1 < NT) {                                                             \
      asm volatile("s_waitcnt vmcnt(2)" ::: "memory");                               \
      WRITEA(PAR ^ 1);                                                               \
    }                                                                                \
    __builtin_amdgcn_sched_barrier(0);                                               \
    if ((TT) + 2 < NT) LOADA(PAR, (TT) + 2);                                         \
    __builtin_amdgcn_sched_barrier(0);                                               \
    if ((TT) + 2 < NT) STAGEB((TT) + 2);                                             \
    __builtin_amdgcn_sched_barrier(0);                                               \
    COMPUTE(PAR, TT);                                                                \
    if ((TT) + 2 < NT)                                                               \
      asm volatile("s_waitcnt vmcnt(6)" ::: "memory");                               \
    else                                                                             \
      asm volatile("s_waitcnt vmcnt(0)" ::: "memory");                               \
    asm volatile("s_waitcnt lgkmcnt(0)" ::: "memory");                               \
    __builtin_amdgcn_s_barrier();                                                    \
  } while (0)

  // prologue: issue order A0, B0, A1, B1 (sched_barrier-pinned)
  LOADA(0, 0);
  __builtin_amdgcn_sched_barrier(0);
  STAGEB(0);
  __builtin_amdgcn_sched_barrier(0);
  LOADA(1, 1);
  __builtin_amdgcn_sched_barrier(0);
  STAGEB(1);
  __builtin_amdgcn_sched_barrier(0);
  asm volatile("s_waitcnt vmcnt(8)" ::: "memory");  // A0 landed
  WRITEA(0);
  asm volatile("s_waitcnt vmcnt(6)" ::: "memory");  // B0 in LDS
  asm volatile("s_waitcnt lgkmcnt(0)" ::: "memory");
  __builtin_amdgcn_s_barrier();

  for (int tt = 0; tt < NT; tt += 2) {
    PSTEP(tt, 0);
    PSTEP(tt + 1, 1);
  }

#pragma unroll
  for (int im = 0; im < 4; ++im)
#pragma unroll
    for (int fn = 0; fn < 4; ++fn) {
      int col = n0 + wn * 64 + fn * 16 + lq;
      float bv = bias[col];
      int rbase = m0 + wm * 64 + im * 16 + hi * 4;
#pragma unroll
      for (int r = 0; r < 4; ++r)
        C[(size_t)(rbase + r) * N + col] = f2bf(acc[im][fn][r] + bv);
    }
#undef LOADA
#undef WRITEA
#undef STAGEB
#undef COMPUTE
#undef PSTEP
}

// ------------- out-proj GEMM (bf16 A, R10-proven): BM=BN=128, BK=32, 3 bufs, vmcnt(4) -------------
__global__ __launch_bounds__(256, 3) void gemm_dp(const u16* __restrict__ A,
                                                  const u16* __restrict__ Wt,
                                                  const float* __restrict__ bias,
                                                  float* __restrict__ Cv,
                                                  int N, int K, int nxl) {
  __shared__ u16 ldsA[3][128 * 32];
  __shared__ u16 ldsB[3][128 * 32];

  int Lb = blockIdx.x;
  int xcd = Lb & 7, slot = Lb >> 3;
  int panel = ((slot >> nxl) << 3) + xcd;
  int x = slot & ((1 << nxl) - 1);
  int y = panel & 31;

  int m0 = y * 128, n0 = x * 128;
  int t = threadIdx.x;
  int lane = t & 63, lq = lane & 15, hi = lane >> 4;
  int w = t >> 6, wm = w >> 1, wn = w & 1;
  int NT = K >> 5;

  auto stage = [&](int q, int kt) {
    u16* lA = &ldsA[q][0];
    u16* lB = &ldsB[q][0];
    int kb = kt * 32;
#pragma unroll
    for (int i = 0; i < 2; ++i) {
      int idx = i * 256 + t;
      int row = idx >> 2, c = idx & 3;
      glds16(&A[(size_t)(m0 + row) * K + kb + ((c ^ ((row >> 1) & 3)) << 3)], lA + idx * 8);
    }
#pragma unroll
    for (int i = 0; i < 2; ++i) {
      int idx = i * 256 + t;
      int row = idx >> 2, c = idx & 3;
      glds16(&Wt[(size_t)(n0 + row) * K + kb + ((c ^ ((row >> 1) & 3)) << 3)], lB + idx * 8);
    }
  };

  f32x4 acc[4][4];
#pragma unroll
  for (int im = 0; im < 4; ++im)
#pragma unroll
    for (int fn = 0; fn < 4; ++fn) acc[im][fn] = (f32x4){0.f, 0.f, 0.f, 0.f};

  stage(0, 0);
  stage(1, 1);
  asm volatile("s_waitcnt vmcnt(4)" ::: "memory");
  __builtin_amdgcn_s_barrier();

  for (int tt = 0; tt < NT; ++tt) {
    int q = tt % 3;
    if (tt + 2 < NT) stage((tt + 2) % 3, tt + 2);
    const u16* lA = &ldsA[q][0];
    const u16* lB = &ldsB[q][0];
    bf16x8 bf[4];
#pragma unroll
    for (int fn = 0; fn < 4; ++fn) {
      int row = wn * 64 + fn * 16 + lq;
      bf[fn] = *(const bf16x8*)&lB[row * 32 + ((hi ^ ((row >> 1) & 3)) << 3)];
    }
    __builtin_amdgcn_s_setprio(1);
#pragma unroll
    for (int im = 0; im < 4; ++im) {
      int row = wm * 64 + im * 16 + lq;
      bf16x8 af = *(const bf16x8*)&lA[row * 32 + ((hi ^ ((row >> 1) & 3)) << 3)];
#pragma unroll
      for (int fn = 0; fn < 4; ++fn)
        acc[im][fn] = __builtin_amdgcn_mfma_f32_16x16x32_bf16(af, bf[fn], acc[im][fn], 0, 0, 0);
    }
    __builtin_amdgcn_s_setprio(0);
    if (tt + 2 < NT)
      asm volatile("s_waitcnt vmcnt(4)" ::: "memory");
    else
      asm volatile("s_waitcnt vmcnt(0)" ::: "memory");
    __builtin_amdgcn_s_barrier();
  }

#pragma unroll
  for (int im = 0; im < 4; ++im)
#pragma unroll
    for (int fn = 0; fn < 4; ++fn) {
      int col = n0 + wn * 64 + fn * 16 + lq;
      float bv = bias[col];
      int rbase = m0 + wm * 64 + im * 16 + hi * 4;
#pragma unroll
      for (int r = 0; r < 4; ++r)
        Cv[(size_t)(rbase + r) * N + col] = acc[im][fn][r] + bv;
    }
}

// ------------- transpose_lv: LV[b][s][h*64+ld] -> LVt[bh][ld][s], sigma-permuted per 32-s -------------
__global__ __launch_bounds__(256) void transpose_lv(const u16* __restrict__ LV,
                                                    u16* __restrict__ out) {
  __shared__ u16 tile[64 * 72];
  int st = blockIdx.x, bh = blockIdx.y;
  int b = bh >> 4, h = bh & 15;
  int t = threadIdx.x;
  int s0 = st * 64;
#pragma unroll
  for (int i = 0; i < 2; ++i) {
    int idx = i * 256 + t;
    int sr = idx >> 3, c8 = idx & 7;
    bf16x8 v = *(const bf16x8*)&LV[(size_t)(b * S_LEN + s0 + sr) * 1024 + h * 64 + c8 * 8];
    int pos = (sr & 32) + ((sr & 12) << 1) + ((sr & 16) >> 2) + (sr & 3);
#pragma unroll
    for (int j = 0; j < 8; ++j) tile[(c8 * 8 + j) * 72 + pos] = (u16)v[j];
  }
  __syncthreads();
  u16* ob = out + (size_t)bh * 64 * S_LEN;
#pragma unroll
  for (int i = 0; i < 2; ++i) {
    int idx = i * 256 + t;
    int ld = idx >> 3, c8 = idx & 7;
    bf16x8 v = *(const bf16x8*)&tile[ld * 72 + c8 * 8];
    *(bf16x8*)&ob[(size_t)ld * S_LEN + s0 + c8 * 8] = v;
  }
}

// ------------- latent flash attention: QBLK=64, 1024 blocks (4/CU), 32KB LDS (R13 version) -------------
__global__ __launch_bounds__(256) void mla_attn5(const u16* __restrict__ Qp,
                                                 const u16* __restrict__ LK,
                                                 const u16* __restrict__ LVt,
                                                 u16* __restrict__ O) {
  __shared__ u16 smem[16384];
  int Lb = blockIdx.x + blockIdx.y * 8;
  int half = Lb >> 9;
  int i0 = Lb & 511;
  int xcd = i0 & 7, ii = i0 >> 3;
  int bh = xcd * 4 + (ii & 3);
  int pr = ii >> 2;
  int qsup = half ? (31 - pr) : pr;
  int b = bh >> 4, h = bh & 15;
  int t = threadIdx.x, w = t >> 6, lane = t & 63, lq = lane & 15, hi = lane >> 4;
  int lq7 = lq & 7;

  const u16* Kb = LK + (size_t)b * S_LEN * 1024 + h * 64;
  const u16* Vb = LVt + (size_t)bh * 64 * S_LEN;
  const float scale = 0.08838834764831845f;

  auto stage = [&](int buf, int k0) {
    u16* lK = smem + buf * 4096;
    u16* lV = smem + 8192 + buf * 4096;
#pragma unroll
    for (int i = 0; i < 2; ++i) {
      int idx = i * 256 + t;
      int row = idx >> 3, c8 = idx & 7;
      glds16(Kb + (size_t)(k0 + row) * 1024 + ((c8 ^ (row & 7)) << 3), lK + idx * 8);
    }
#pragma unroll
    for (int i = 0; i < 2; ++i) {
      int idx = i * 256 + t;
      int row = idx >> 3, c8 = idx & 7;
      glds16(Vb + (size_t)row * S_LEN + k0 + ((c8 ^ (row & 7)) << 3), lV + idx * 8);
    }
  };

  int qb = qsup * 64;
  int nt = qsup + 1;
  int q0 = qb + w * 16;
  int kmax = q0 + 16;

  bf16x8 qf[2];
  {
    const u16* Qrow = Qp + (size_t)(b * S_LEN + q0 + lq) * 1024 + h * 64;
    qf[0] = *(const bf16x8*)&Qrow[hi * 8];
    qf[1] = *(const bf16x8*)&Qrow[32 + hi * 8];
  }

  f32x4 acc[4];
#pragma unroll
  for (int f = 0; f < 4; ++f) acc[f] = (f32x4){0.f, 0.f, 0.f, 0.f};
  float m = -1e30f, l = 0.f;

  stage(0, 0);
  __syncthreads();
  for (int tt = 0; tt < nt; ++tt) {
    int cur = tt & 1;
    if (tt + 1 < nt) stage(cur ^ 1, (tt + 1) * 64);
    int k0 = tt * 64;
    if (k0 < kmax) {
      const u16* lK = smem + cur * 4096;
      const u16* lV = smem + 8192 + cur * 4096;
      f32x4 sc[4];
#pragma unroll
      for (int kf = 0; kf < 4; ++kf) sc[kf] = (f32x4){0.f, 0.f, 0.f, 0.f};
      __builtin_amdgcn_s_setprio(1);
#pragma unroll
      for (int kf = 0; kf < 4; ++kf) {
        const u16* kr = lK + (kf * 16 + lq) * 64;
#pragma unroll
        for (int d0 = 0; d0 < 2; ++d0) {
          bf16x8 af = *(const bf16x8*)&kr[(((d0 << 2) + hi) ^ lq7) << 3];
          sc[kf] = __builtin_amdgcn_mfma_f32_16x16x32_bf16(af, qf[d0], sc[kf], 0, 0, 0);
        }
      }
      __builtin_amdgcn_s_setprio(0);
      int q = q0 + lq;
      float sv[16];
#pragma unroll
      for (int kf = 0; kf < 4; ++kf)
#pragma unroll
        for (int r = 0; r < 4; ++r) sv[kf * 4 + r] = sc[kf][r] * scale;
      if (k0 + 63 > q0) {
#pragma unroll
        for (int kf = 0; kf < 4; ++kf)
#pragma unroll
          for (int r = 0; r < 4; ++r)
            if (k0 + kf * 16 + hi * 4 + r > q) sv[kf * 4 + r] = -1e30f;
      }
      float tm = sv[0];
#pragma unroll
      for (int j = 1; j < 16; ++j) tm = fmaxf(tm, sv[j]);
      tm = fmaxf(tm, __shfl_xor(tm, 16));
      tm = fmaxf(tm, __shfl_xor(tm, 32));
      float p[16], ps = 0.f;
      if (__all(tm <= m + 8.f)) {
#pragma unroll
        for (int j = 0; j < 16; ++j) { p[j] = __expf(sv[j] - m); ps += p[j]; }
        ps += __shfl_xor(ps, 16);
        ps += __shfl_xor(ps, 32);
        l += ps;
      } else {
        float mnew = fmaxf(m, tm);
        float alpha = __expf(m - mnew);
#pragma unroll
        for (int j = 0; j < 16; ++j) { p[j] = __expf(sv[j] - mnew); ps += p[j]; }
        ps += __shfl_xor(ps, 16);
        ps += __shfl_xor(ps, 32);
        l = l * alpha + ps;
        m = mnew;
#pragma unroll
        for (int f = 0; f < 4; ++f) {
          acc[f][0] *= alpha; acc[f][1] *= alpha;
          acc[f][2] *= alpha; acc[f][3] *= alpha;
        }
      }
      bf16x8 pb[2];
#pragma unroll
      for (int ks = 0; ks < 2; ++ks) {
        union { u32x4 u; bf16x8 v; } pu;
#pragma unroll
        for (int wd = 0; wd < 4; ++wd) pu.u[wd] = pk2(p[ks * 8 + 2 * wd], p[ks * 8 + 2 * wd + 1]);
        pb[ks] = pu.v;
      }
      __builtin_amdgcn_s_setprio(1);
#pragma unroll
      for (int f = 0; f < 4; ++f) {
        const u16* vr = lV + (f * 16 + lq) * 64;
#pragma unroll
        for (int ks = 0; ks < 2; ++ks) {
          bf16x8 va = *(const bf16x8*)&vr[(((ks << 2) + hi) ^ lq7) << 3];
          acc[f] = __builtin_amdgcn_mfma_f32_16x16x32_bf16(va, pb[ks], acc[f], 0, 0, 0);
        }
      }
      __builtin_amdgcn_s_setprio(0);
    }
    __syncthreads();
  }
  {
    float inv = 1.f / l;
    int qloc = w * 16 + lq;
#pragma unroll
    for (int f = 0; f < 4; ++f)
#pragma unroll
      for (int r = 0; r < 4; ++r) {
        int col = f * 16 + hi * 4 + r;
        smem[qloc * 64 + (((col >> 3) ^ lq7) << 3) + (col & 7)] = f2bf(acc[f][r] * inv);
      }
  }
  __syncthreads();
#pragma unroll
  for (int i = 0; i < 2; ++i) {
    int cid = i * 256 + t;
    int q = cid >> 3, ch = cid & 7;
    bf16x8 v = *(const bf16x8*)&smem[q * 64 + ((ch ^ (q & 7)) << 3)];
    *(bf16x8*)&O[(size_t)(b * S_LEN + qb + q) * 1024 + h * 64 + (ch << 3)] = v;
  }
}

extern "C" void kernel_launch(void* const* d_in, const int* in_sizes, int n_in,
                              void* d_out, int out_size, void* d_ws, size_t ws_size,
                              hipStream_t stream) {
  const float* queries = (const float*)d_in[0];
  const float* keys    = (const float*)d_in[1];
  const float* values  = (const float*)d_in[2];
  const float* Wq      = (const float*)d_in[3];
  const float* bq      = (const float*)d_in[4];
  const float* Wlk     = (const float*)d_in[5];
  const float* blk     = (const float*)d_in[6];
  const float* Wlv     = (const float*)d_in[7];
  const float* blv     = (const float*)d_in[8];
  const float* Wkr     = (const float*)d_in[9];
  const float* Wvr     = (const float*)d_in[10];
  const float* Wout    = (const float*)d_in[11];
  const float* bout    = (const float*)d_in[12];

  u16* ws = (u16*)d_ws;
  u16* WqBf  = ws; ws += (size_t)2048 * 2048;
  u16* WkrBf = ws; ws += 64 * 128;
  u16* WvrBf = ws; ws += 64 * 128;
  u16* WoutT = ws; ws += (size_t)2048 * 2048;
  u16* WlkT  = ws; ws += (size_t)1024 * 2048;
  u16* WlvT  = ws; ws += (size_t)1024 * 2048;
  u16* Wq2T  = ws; ws += (size_t)1024 * 2048;
  u16* W2T   = ws; ws += (size_t)2048 * 1024;
  float* bq2 = (float*)ws; ws += 2048;
  u16* Qp    = ws; ws += (size_t)4096 * 1024;
  u16* LKb   = ws; ws += (size_t)4096 * 1024;
  u16* LVb   = ws; ws += (size_t)4096 * 1024;
  u16* LVt   = ws; ws += (size_t)32 * 64 * S_LEN;
  u16* Ob    = ws; ws += (size_t)4096 * 1024;

  dim3 blk256(256);
  cast_f32_bf16<<<dim3(2048), blk256, 0, stream>>>(Wq, WqBf);
  cast2_f32_bf16<<<dim3(4, 2), blk256, 0, stream>>>(Wkr, Wvr, WkrBf, WvrBf);

  transpose2_f32_bf16<<<dim3(16, 32, 2), blk256, 0, stream>>>(Wlk, Wlv, WlkT, WlvT, 2048, 1024);
  transpose_f32_bf16<<<dim3(32, 32), blk256, 0, stream>>>(Wout, WoutT, 2048, 2048);

  absorb_q<<<dim3(16, 16), blk256, 0, stream>>>(WkrBf, WqBf, Wq2T);
  absorb_o<<<dim3(16, 16), blk256, 0, stream>>>(WoutT, WvrBf, W2T);
  absorb_bq<<<dim3(4), blk256, 0, stream>>>(bq, Wkr, bq2);

  // proj: fp32 A LDS-staged (R12 schedule).  768 blocks = 3/CU.
  gemm_projf<<<dim3(768), blk256, 0, stream>>>(
      queries, keys, values, Wq2T, WlkT, WlvT, bq2, blk, blv, Qp, LKb, LVb);

  transpose_lv<<<dim3(32, 32), blk256, 0, stream>>>(LVb, LVt);

  mla_attn5<<<dim3(8, 128), blk256, 0, stream>>>(Qp, LKb, LVt, Ob);

  // out: N=2048 (nxl=4, 16 x-tiles), 32 panels * 16 = 512 blocks = 2/CU
  gemm_dp<<<dim3(512), blk256, 0, stream>>>(
      Ob, W2T, bout, (float*)d_out, 2048, 1024, 4);
}

// Round 18
// 176.635 us; speedup vs baseline: 2.1570x; 1.0327x over previous
//
#include <hip/hip_runtime.h>

#define S_LEN 2048
#define NH 16

typedef unsigned short u16;
typedef __attribute__((ext_vector_type(8))) short bf16x8;
typedef __attribute__((ext_vector_type(4))) short s16x4;
typedef __attribute__((ext_vector_type(4))) unsigned short u16x4;
typedef __attribute__((ext_vector_type(4))) unsigned int u32x4;
typedef __attribute__((ext_vector_type(4))) float f32x4;

__device__ __forceinline__ u16 f2bf(float f) {
  union { float f; unsigned int i; } x; x.f = f;
  unsigned int r = x.i + 0x7FFFu + ((x.i >> 16) & 1u);
  return (u16)(r >> 16);
}
__device__ __forceinline__ unsigned pk2(float lo, float hi) {
  unsigned r;
  asm("v_cvt_pk_bf16_f32 %0, %1, %2" : "=v"(r) : "v"(lo), "v"(hi));
  return r;
}
__device__ __forceinline__ void glds16(const void* g, void* l) {
  __builtin_amdgcn_global_load_lds((const __attribute__((address_space(1))) void*)g,
                                   (__attribute__((address_space(3))) void*)l, 16, 0, 0);
}

// ---------------- fused weight casts: Wq (2048 blk) + Wkr (4) + Wvr (4) ----------------
__global__ __launch_bounds__(256) void cast_w(const float* __restrict__ Wq,
                                              const float* __restrict__ Wkr,
                                              const float* __restrict__ Wvr,
                                              u16* __restrict__ WqBf,
                                              u16* __restrict__ WkrBf,
                                              u16* __restrict__ WvrBf) {
  int bx = blockIdx.x;
  const float* in;
  u16* out;
  size_t base;
  if (bx < 2048) { in = Wq;  out = WqBf;  base = (size_t)bx * 2048; }
  else if (bx < 2052) { in = Wkr; out = WkrBf; base = (size_t)(bx - 2048) * 2048; }
  else { in = Wvr; out = WvrBf; base = (size_t)(bx - 2052) * 2048; }
  size_t i = base + (size_t)threadIdx.x * 8;
  f32x4 a = *(const f32x4*)&in[i];
  f32x4 b = *(const f32x4*)&in[i + 4];
  u32x4 o;
  o[0] = pk2(a[0], a[1]);
  o[1] = pk2(a[2], a[3]);
  o[2] = pk2(b[0], b[1]);
  o[3] = pk2(b[2], b[3]);
  *(u32x4*)&out[i] = o;
}

// ---------------- fused weight transposes: z=0 Wlk, z=1 Wlv (N=1024), z=2 Wout (N=2048) ----------------
__global__ __launch_bounds__(256) void transpose_w(const float* __restrict__ Wlk,
                                                   const float* __restrict__ Wlv,
                                                   const float* __restrict__ Wout,
                                                   u16* __restrict__ WlkT,
                                                   u16* __restrict__ WlvT,
                                                   u16* __restrict__ WoutT) {
  int z = blockIdx.z;
  int N = (z == 2) ? 2048 : 1024;
  if (z < 2 && blockIdx.x >= 16) return;  // uniform per-block exit
  const float* in = z == 0 ? Wlk : (z == 1 ? Wlv : Wout);
  u16* out = z == 0 ? WlkT : (z == 1 ? WlvT : WoutT);
  const int K = 2048;
  __shared__ u16 tile[64][72];
  int k0 = blockIdx.y * 64, n0 = blockIdx.x * 64;
  int t = threadIdx.x;
#pragma unroll
  for (int i = 0; i < 4; ++i) {
    int idx = i * 256 + t;
    int r = idx >> 4;
    int c4 = (idx & 15) << 2;
    f32x4 v = *(const f32x4*)&in[(size_t)(k0 + r) * N + n0 + c4];
#pragma unroll
    for (int j = 0; j < 4; ++j) tile[r][c4 + j] = f2bf(v[j]);
  }
  __syncthreads();
#pragma unroll
  for (int i = 0; i < 4; ++i) {
    int idx = i * 256 + t;
    int r = idx >> 4;
    int c4 = (idx & 15) << 2;
    u16x4 v;
    v[0] = tile[c4 + 0][r];
    v[1] = tile[c4 + 1][r];
    v[2] = tile[c4 + 2][r];
    v[3] = tile[c4 + 3][r];
    *(u16x4*)&out[(size_t)(n0 + r) * K + k0 + c4] = v;
  }
}

// ------------- absorb_q (+ absorb_bq folded into kb==16 column) -------------
__global__ __launch_bounds__(256) void absorb_q(const u16* __restrict__ Wkr,
                                                const u16* __restrict__ Wqb,
                                                u16* __restrict__ Wq2T,
                                                const float* __restrict__ bq,
                                                const float* __restrict__ WkrF,
                                                float* __restrict__ bq2) {
  int kb = blockIdx.x, h = blockIdx.y;
  int t = threadIdx.x;
  if (kb == 16) {  // absorb_bq: 4 blocks (h<4) x 256 threads = 1024 outputs
    if (h >= 4) return;
    int n = h * 256 + t;
    int hh = n >> 6, ld = n & 63;
    float s = 0.f;
#pragma unroll 8
    for (int dk = 0; dk < 128; ++dk) s += bq[hh * 128 + dk] * WkrF[ld * 128 + dk];
    bq2[n] = s;
    return;
  }
  int w = t >> 6, lane = t & 63, lq = lane & 15, hi = lane >> 4;
  int k0 = kb * 128 + w * 32;
  f32x4 acc[4][2];
#pragma unroll
  for (int i = 0; i < 4; ++i)
#pragma unroll
    for (int j = 0; j < 2; ++j) acc[i][j] = (f32x4){0.f, 0.f, 0.f, 0.f};
#pragma unroll
  for (int kk = 0; kk < 4; ++kk) {
    bf16x8 a[4], bb[2];
#pragma unroll
    for (int fld = 0; fld < 4; ++fld)
      a[fld] = *(const bf16x8*)&Wkr[(fld * 16 + lq) * 128 + kk * 32 + hi * 8];
#pragma unroll
    for (int fk = 0; fk < 2; ++fk)
      bb[fk] = *(const bf16x8*)&Wqb[(size_t)(k0 + fk * 16 + lq) * 2048 + h * 128 + kk * 32 + hi * 8];
#pragma unroll
    for (int fld = 0; fld < 4; ++fld)
#pragma unroll
      for (int fk = 0; fk < 2; ++fk)
        acc[fld][fk] = __builtin_amdgcn_mfma_f32_16x16x32_bf16(a[fld], bb[fk], acc[fld][fk], 0, 0, 0);
  }
#pragma unroll
  for (int fld = 0; fld < 4; ++fld)
#pragma unroll
    for (int fk = 0; fk < 2; ++fk)
#pragma unroll
      for (int r = 0; r < 4; ++r)
        Wq2T[(size_t)(h * 64 + fld * 16 + hi * 4 + r) * 2048 + k0 + fk * 16 + lq] =
            f2bf(acc[fld][fk][r]);
}

// ------------- absorb_o -------------
__global__ __launch_bounds__(256) void absorb_o(const u16* __restrict__ WoutT,
                                                const u16* __restrict__ Wvr,
                                                u16* __restrict__ W2T) {
  int nb = blockIdx.x, h = blockIdx.y;
  int t = threadIdx.x, w = t >> 6, lane = t & 63, lq = lane & 15, hi = lane >> 4;
  int n0 = nb * 128 + w * 32;
  f32x4 acc[2][4];
#pragma unroll
  for (int i = 0; i < 2; ++i)
#pragma unroll
    for (int j = 0; j < 4; ++j) acc[i][j] = (f32x4){0.f, 0.f, 0.f, 0.f};
#pragma unroll
  for (int kk = 0; kk < 4; ++kk) {
    bf16x8 a[2], bb[4];
#pragma unroll
    for (int fn = 0; fn < 2; ++fn)
      a[fn] = *(const bf16x8*)&WoutT[(size_t)(n0 + fn * 16 + lq) * 2048 + h * 128 + kk * 32 + hi * 8];
#pragma unroll
    for (int fld = 0; fld < 4; ++fld)
      bb[fld] = *(const bf16x8*)&Wvr[(fld * 16 + lq) * 128 + kk * 32 + hi * 8];
#pragma unroll
    for (int fn = 0; fn < 2; ++fn)
#pragma unroll
      for (int fld = 0; fld < 4; ++fld)
        acc[fn][fld] = __builtin_amdgcn_mfma_f32_16x16x32_bf16(a[fn], bb[fld], acc[fn][fld], 0, 0, 0);
  }
#pragma unroll
  for (int fn = 0; fn < 2; ++fn)
#pragma unroll
    for (int fld = 0; fld < 4; ++fld)
#pragma unroll
      for (int r = 0; r < 4; ++r)
        W2T[(size_t)(n0 + fn * 16 + hi * 4 + r) * 1024 + h * 64 + fld * 16 + lq] =
            f2bf(acc[fn][fld][r]);
}

// ------------- proj GEMM, fp32 A reg-staged through LDS (R12/R17 schedule, 113-116us) -------------
__global__ __launch_bounds__(256, 3) void gemm_projf(const float* __restrict__ A0,
                                                     const float* __restrict__ A1,
                                                     const float* __restrict__ A2,
                                                     const u16* __restrict__ W0,
                                                     const u16* __restrict__ W1,
                                                     const u16* __restrict__ W2,
                                                     const float* __restrict__ b0,
                                                     const float* __restrict__ b1,
                                                     const float* __restrict__ b2,
                                                     u16* __restrict__ C0,
                                                     u16* __restrict__ C1,
                                                     u16* __restrict__ C2) {
  const int N = 1024, K = 2048, nxl = 3, NT = 64;
  __shared__ u16 abuf[2][128 * 32];
  __shared__ u16 bbuf[3][128 * 32];

  int Lb = blockIdx.x;
  int xcd = Lb & 7, slot = Lb >> 3;
  int panel = ((slot >> nxl) << 3) + xcd;
  int x = slot & ((1 << nxl) - 1);
  int z = panel >> 5, y = panel & 31;

  const float* A = z == 0 ? A0 : (z == 1 ? A1 : A2);
  const u16* Wt = z == 0 ? W0 : (z == 1 ? W1 : W2);
  const float* bias = z == 0 ? b0 : (z == 1 ? b1 : b2);
  u16* C = z == 0 ? C0 : (z == 1 ? C1 : C2);

  int m0 = y * 128, n0 = x * 128;
  int t = threadIdx.x;
  int lane = t & 63, lq = lane & 15, hi = lane >> 4;
  int w = t >> 6, wm = w >> 1, wn = w & 1;

  struct a16 { f32x4 lo, hi; };
  a16 areg[2][2];

  f32x4 acc[4][4];
#pragma unroll
  for (int im = 0; im < 4; ++im)
#pragma unroll
    for (int fn = 0; fn < 4; ++fn) acc[im][fn] = (f32x4){0.f, 0.f, 0.f, 0.f};

#define LOADA(SLOT, KT)                                                              \
  do {                                                                               \
    int kb_ = (KT) * 32;                                                             \
    _Pragma("unroll") for (int i = 0; i < 2; ++i) {                                  \
      int idx = i * 256 + t, row = idx >> 2, c = idx & 3;                            \
      const float* ap = &A[(size_t)(m0 + row) * K + kb_ + ((c ^ ((row >> 1) & 3)) << 3)]; \
      areg[SLOT][i].lo = *(const f32x4*)ap;                                          \
      areg[SLOT][i].hi = *(const f32x4*)(ap + 4);                                    \
    }                                                                                \
  } while (0)

#define WRITEA(SLOT)                                                                 \
  do {                                                                               \
    _Pragma("unroll") for (int i = 0; i < 2; ++i) {                                  \
      u32x4 o;                                                                       \
      o[0] = pk2(areg[SLOT][i].lo[0], areg[SLOT][i].lo[1]);                          \
      o[1] = pk2(areg[SLOT][i].lo[2], areg[SLOT][i].lo[3]);                          \
      o[2] = pk2(areg[SLOT][i].hi[0], areg[SLOT][i].hi[1]);                          \
      o[3] = pk2(areg[SLOT][i].hi[2], areg[SLOT][i].hi[3]);                          \
      *(u32x4*)&abuf[SLOT][(i * 256 + t) * 8] = o;                                   \
    }                                                                                \
  } while (0)

#define STAGEB(KT)                                                                   \
  do {                                                                               \
    int kb_ = (KT) * 32;                                                             \
    u16* lB_ = &bbuf[(KT) % 3][0];                                                   \
    _Pragma("unroll") for (int i = 0; i < 2; ++i) {                                  \
      int idx = i * 256 + t, row = idx >> 2, c = idx & 3;                            \
      glds16(&Wt[(size_t)(n0 + row) * K + kb_ + ((c ^ ((row >> 1) & 3)) << 3)], lB_ + idx * 8); \
    }                                                                                \
  } while (0)

#define COMPUTE(PAR, TT)                                                             \
  do {                                                                               \
    const u16* lB_ = &bbuf[(TT) % 3][0];                                             \
    bf16x8 bf[4];                                                                    \
    _Pragma("unroll") for (int fn = 0; fn < 4; ++fn) {                               \
      int row = wn * 64 + fn * 16 + lq;                                              \
      bf[fn] = *(const bf16x8*)&lB_[row * 32 + ((hi ^ ((row >> 1) & 3)) << 3)];      \
    }                                                                                \
    __builtin_amdgcn_s_setprio(1);                                                   \
    _Pragma("unroll") for (int im = 0; im < 4; ++im) {                               \
      int row = wm * 64 + im * 16 + lq;                                              \
      bf16x8 af = *(const bf16x8*)&abuf[PAR][row * 32 + ((hi ^ ((row >> 1) & 3)) << 3)]; \
      _Pragma("unroll") for (int fn = 0; fn < 4; ++fn)                               \
        acc[im][fn] = __builtin_amdgcn_mfma_f32_16x16x32_bf16(af, bf[fn], acc[im][fn], 0, 0, 0); \
    }                                                                                \
    __builtin_amdgcn_s_setprio(0);                                                   \
  } while (0)

#define PSTEP(TT, PAR)                                                               \
  do {                                                                               \
    if ((TT) + 1 < NT) {                                                             \
      asm volatile("s_waitcnt vmcnt(2)" ::: "memory");                               \
      WRITEA(PAR ^ 1);                                                               \
    }                                                                                \
    __builtin_amdgcn_sched_barrier(0);                                               \
    if ((TT) + 2 < NT) LOADA(PAR, (TT) + 2);                                         \
    __builtin_amdgcn_sched_barrier(0);                                               \
    if ((TT) + 2 < NT) STAGEB((TT) + 2);                                             \
    __builtin_amdgcn_sched_barrier(0);                                               \
    COMPUTE(PAR, TT);                                                                \
    if ((TT) + 2 < NT)                                                               \
      asm volatile("s_waitcnt vmcnt(6)" ::: "memory");                               \
    else                                                                             \
      asm volatile("s_waitcnt vmcnt(0)" ::: "memory");                               \
    asm volatile("s_waitcnt lgkmcnt(0)" ::: "memory");                               \
    __builtin_amdgcn_s_barrier();                                                    \
  } while (0)

  LOADA(0, 0);
  __builtin_amdgcn_sched_barrier(0);
  STAGEB(0);
  __builtin_amdgcn_sched_barrier(0);
  LOADA(1, 1);
  __builtin_amdgcn_sched_barrier(0);
  STAGEB(1);
  __builtin_amdgcn_sched_barrier(0);
  asm volatile("s_waitcnt vmcnt(8)" ::: "memory");
  WRITEA(0);
  asm volatile("s_waitcnt vmcnt(6)" ::: "memory");
  asm volatile("s_waitcnt lgkmcnt(0)" ::: "memory");
  __builtin_amdgcn_s_barrier();

  for (int tt = 0; tt < NT; tt += 2) {
    PSTEP(tt, 0);
    PSTEP(tt + 1, 1);
  }

#pragma unroll
  for (int im = 0; im < 4; ++im)
#pragma unroll
    for (int fn = 0; fn < 4; ++fn) {
      int col = n0 + wn * 64 + fn * 16 + lq;
      float bv = bias[col];
      int rbase = m0 + wm * 64 + im * 16 + hi * 4;
#pragma unroll
      for (int r = 0; r < 4; ++r)
        C[(size_t)(rbase + r) * N + col] = f2bf(acc[im][fn][r] + bv);
    }
#undef LOADA
#undef WRITEA
#undef STAGEB
#undef COMPUTE
#undef PSTEP
}

// ------------- out-proj GEMM (bf16 A, R10-proven): BM=BN=128, BK=32, 3 bufs, vmcnt(4) -------------
__global__ __launch_bounds__(256, 3) void gemm_dp(const u16* __restrict__ A,
                                                  const u16* __restrict__ Wt,
                                                  const float* __restrict__ bias,
                                                  float* __restrict__ Cv,
                                                  int N, int K, int nxl) {
  __shared__ u16 ldsA[3][128 * 32];
  __shared__ u16 ldsB[3][128 * 32];

  int Lb = blockIdx.x;
  int xcd = Lb & 7, slot = Lb >> 3;
  int panel = ((slot >> nxl) << 3) + xcd;
  int x = slot & ((1 << nxl) - 1);
  int y = panel & 31;

  int m0 = y * 128, n0 = x * 128;
  int t = threadIdx.x;
  int lane = t & 63, lq = lane & 15, hi = lane >> 4;
  int w = t >> 6, wm = w >> 1, wn = w & 1;
  int NT = K >> 5;

  auto stage = [&](int q, int kt) {
    u16* lA = &ldsA[q][0];
    u16* lB = &ldsB[q][0];
    int kb = kt * 32;
#pragma unroll
    for (int i = 0; i < 2; ++i) {
      int idx = i * 256 + t;
      int row = idx >> 2, c = idx & 3;
      glds16(&A[(size_t)(m0 + row) * K + kb + ((c ^ ((row >> 1) & 3)) << 3)], lA + idx * 8);
    }
#pragma unroll
    for (int i = 0; i < 2; ++i) {
      int idx = i * 256 + t;
      int row = idx >> 2, c = idx & 3;
      glds16(&Wt[(size_t)(n0 + row) * K + kb + ((c ^ ((row >> 1) & 3)) << 3)], lB + idx * 8);
    }
  };

  f32x4 acc[4][4];
#pragma unroll
  for (int im = 0; im < 4; ++im)
#pragma unroll
    for (int fn = 0; fn < 4; ++fn) acc[im][fn] = (f32x4){0.f, 0.f, 0.f, 0.f};

  stage(0, 0);
  stage(1, 1);
  asm volatile("s_waitcnt vmcnt(4)" ::: "memory");
  __builtin_amdgcn_s_barrier();

  for (int tt = 0; tt < NT; ++tt) {
    int q = tt % 3;
    if (tt + 2 < NT) stage((tt + 2) % 3, tt + 2);
    const u16* lA = &ldsA[q][0];
    const u16* lB = &ldsB[q][0];
    bf16x8 bf[4];
#pragma unroll
    for (int fn = 0; fn < 4; ++fn) {
      int row = wn * 64 + fn * 16 + lq;
      bf[fn] = *(const bf16x8*)&lB[row * 32 + ((hi ^ ((row >> 1) & 3)) << 3)];
    }
    __builtin_amdgcn_s_setprio(1);
#pragma unroll
    for (int im = 0; im < 4; ++im) {
      int row = wm * 64 + im * 16 + lq;
      bf16x8 af = *(const bf16x8*)&lA[row * 32 + ((hi ^ ((row >> 1) & 3)) << 3)];
#pragma unroll
      for (int fn = 0; fn < 4; ++fn)
        acc[im][fn] = __builtin_amdgcn_mfma_f32_16x16x32_bf16(af, bf[fn], acc[im][fn], 0, 0, 0);
    }
    __builtin_amdgcn_s_setprio(0);
    if (tt + 2 < NT)
      asm volatile("s_waitcnt vmcnt(4)" ::: "memory");
    else
      asm volatile("s_waitcnt vmcnt(0)" ::: "memory");
    __builtin_amdgcn_s_barrier();
  }

#pragma unroll
  for (int im = 0; im < 4; ++im)
#pragma unroll
    for (int fn = 0; fn < 4; ++fn) {
      int col = n0 + wn * 64 + fn * 16 + lq;
      float bv = bias[col];
      int rbase = m0 + wm * 64 + im * 16 + hi * 4;
#pragma unroll
      for (int r = 0; r < 4; ++r)
        Cv[(size_t)(rbase + r) * N + col] = acc[im][fn][r] + bv;
    }
}

// ------------- transpose_lv: LV[b][s][h*64+ld] -> LVt[bh][ld][s], sigma-permuted per 32-s -------------
__global__ __launch_bounds__(256) void transpose_lv(const u16* __restrict__ LV,
                                                    u16* __restrict__ out) {
  __shared__ u16 tile[64 * 72];
  int st = blockIdx.x, bh = blockIdx.y;
  int b = bh >> 4, h = bh & 15;
  int t = threadIdx.x;
  int s0 = st * 64;
#pragma unroll
  for (int i = 0; i < 2; ++i) {
    int idx = i * 256 + t;
    int sr = idx >> 3, c8 = idx & 7;
    bf16x8 v = *(const bf16x8*)&LV[(size_t)(b * S_LEN + s0 + sr) * 1024 + h * 64 + c8 * 8];
    int pos = (sr & 32) + ((sr & 12) << 1) + ((sr & 16) >> 2) + (sr & 3);
#pragma unroll
    for (int j = 0; j < 8; ++j) tile[(c8 * 8 + j) * 72 + pos] = (u16)v[j];
  }
  __syncthreads();
  u16* ob = out + (size_t)bh * 64 * S_LEN;
#pragma unroll
  for (int i = 0; i < 2; ++i) {
    int idx = i * 256 + t;
    int ld = idx >> 3, c8 = idx & 7;
    bf16x8 v = *(const bf16x8*)&tile[ld * 72 + c8 * 8];
    *(bf16x8*)&ob[(size_t)ld * S_LEN + s0 + c8 * 8] = v;
  }
}

// ------------- latent flash attention: QBLK=64, 1024 blocks (4/CU), 32KB LDS (R13 version) -------------
__global__ __launch_bounds__(256) void mla_attn5(const u16* __restrict__ Qp,
                                                 const u16* __restrict__ LK,
                                                 const u16* __restrict__ LVt,
                                                 u16* __restrict__ O) {
  __shared__ u16 smem[16384];
  int Lb = blockIdx.x + blockIdx.y * 8;
  int half = Lb >> 9;
  int i0 = Lb & 511;
  int xcd = i0 & 7, ii = i0 >> 3;
  int bh = xcd * 4 + (ii & 3);
  int pr = ii >> 2;
  int qsup = half ? (31 - pr) : pr;
  int b = bh >> 4, h = bh & 15;
  int t = threadIdx.x, w = t >> 6, lane = t & 63, lq = lane & 15, hi = lane >> 4;
  int lq7 = lq & 7;

  const u16* Kb = LK + (size_t)b * S_LEN * 1024 + h * 64;
  const u16* Vb = LVt + (size_t)bh * 64 * S_LEN;
  const float scale = 0.08838834764831845f;

  auto stage = [&](int buf, int k0) {
    u16* lK = smem + buf * 4096;
    u16* lV = smem + 8192 + buf * 4096;
#pragma unroll
    for (int i = 0; i < 2; ++i) {
      int idx = i * 256 + t;
      int row = idx >> 3, c8 = idx & 7;
      glds16(Kb + (size_t)(k0 + row) * 1024 + ((c8 ^ (row & 7)) << 3), lK + idx * 8);
    }
#pragma unroll
    for (int i = 0; i < 2; ++i) {
      int idx = i * 256 + t;
      int row = idx >> 3, c8 = idx & 7;
      glds16(Vb + (size_t)row * S_LEN + k0 + ((c8 ^ (row & 7)) << 3), lV + idx * 8);
    }
  };

  int qb = qsup * 64;
  int nt = qsup + 1;
  int q0 = qb + w * 16;
  int kmax = q0 + 16;

  bf16x8 qf[2];
  {
    const u16* Qrow = Qp + (size_t)(b * S_LEN + q0 + lq) * 1024 + h * 64;
    qf[0] = *(const bf16x8*)&Qrow[hi * 8];
    qf[1] = *(const bf16x8*)&Qrow[32 + hi * 8];
  }

  f32x4 acc[4];
#pragma unroll
  for (int f = 0; f < 4; ++f) acc[f] = (f32x4){0.f, 0.f, 0.f, 0.f};
  float m = -1e30f, l = 0.f;

  stage(0, 0);
  __syncthreads();
  for (int tt = 0; tt < nt; ++tt) {
    int cur = tt & 1;
    if (tt + 1 < nt) stage(cur ^ 1, (tt + 1) * 64);
    int k0 = tt * 64;
    if (k0 < kmax) {
      const u16* lK = smem + cur * 4096;
      const u16* lV = smem + 8192 + cur * 4096;
      f32x4 sc[4];
#pragma unroll
      for (int kf = 0; kf < 4; ++kf) sc[kf] = (f32x4){0.f, 0.f, 0.f, 0.f};
      __builtin_amdgcn_s_setprio(1);
#pragma unroll
      for (int kf = 0; kf < 4; ++kf) {
        const u16* kr = lK + (kf * 16 + lq) * 64;
#pragma unroll
        for (int d0 = 0; d0 < 2; ++d0) {
          bf16x8 af = *(const bf16x8*)&kr[(((d0 << 2) + hi) ^ lq7) << 3];
          sc[kf] = __builtin_amdgcn_mfma_f32_16x16x32_bf16(af, qf[d0], sc[kf], 0, 0, 0);
        }
      }
      __builtin_amdgcn_s_setprio(0);
      int q = q0 + lq;
      float sv[16];
#pragma unroll
      for (int kf = 0; kf < 4; ++kf)
#pragma unroll
        for (int r = 0; r < 4; ++r) sv[kf * 4 + r] = sc[kf][r] * scale;
      if (k0 + 63 > q0) {
#pragma unroll
        for (int kf = 0; kf < 4; ++kf)
#pragma unroll
          for (int r = 0; r < 4; ++r)
            if (k0 + kf * 16 + hi * 4 + r > q) sv[kf * 4 + r] = -1e30f;
      }
      float tm = sv[0];
#pragma unroll
      for (int j = 1; j < 16; ++j) tm = fmaxf(tm, sv[j]);
      tm = fmaxf(tm, __shfl_xor(tm, 16));
      tm = fmaxf(tm, __shfl_xor(tm, 32));
      float p[16], ps = 0.f;
      if (__all(tm <= m + 8.f)) {
#pragma unroll
        for (int j = 0; j < 16; ++j) { p[j] = __expf(sv[j] - m); ps += p[j]; }
        ps += __shfl_xor(ps, 16);
        ps += __shfl_xor(ps, 32);
        l += ps;
      } else {
        float mnew = fmaxf(m, tm);
        float alpha = __expf(m - mnew);
#pragma unroll
        for (int j = 0; j < 16; ++j) { p[j] = __expf(sv[j] - mnew); ps += p[j]; }
        ps += __shfl_xor(ps, 16);
        ps += __shfl_xor(ps, 32);
        l = l * alpha + ps;
        m = mnew;
#pragma unroll
        for (int f = 0; f < 4; ++f) {
          acc[f][0] *= alpha; acc[f][1] *= alpha;
          acc[f][2] *= alpha; acc[f][3] *= alpha;
        }
      }
      bf16x8 pb[2];
#pragma unroll
      for (int ks = 0; ks < 2; ++ks) {
        union { u32x4 u; bf16x8 v; } pu;
#pragma unroll
        for (int wd = 0; wd < 4; ++wd) pu.u[wd] = pk2(p[ks * 8 + 2 * wd], p[ks * 8 + 2 * wd + 1]);
        pb[ks] = pu.v;
      }
      __builtin_amdgcn_s_setprio(1);
#pragma unroll
      for (int f = 0; f < 4; ++f) {
        const u16* vr = lV + (f * 16 + lq) * 64;
#pragma unroll
        for (int ks = 0; ks < 2; ++ks) {
          bf16x8 va = *(const bf16x8*)&vr[(((ks << 2) + hi) ^ lq7) << 3];
          acc[f] = __builtin_amdgcn_mfma_f32_16x16x32_bf16(va, pb[ks], acc[f], 0, 0, 0);
        }
      }
      __builtin_amdgcn_s_setprio(0);
    }
    __syncthreads();
  }
  {
    float inv = 1.f / l;
    int qloc = w * 16 + lq;
#pragma unroll
    for (int f = 0; f < 4; ++f)
#pragma unroll
      for (int r = 0; r < 4; ++r) {
        int col = f * 16 + hi * 4 + r;
        smem[qloc * 64 + (((col >> 3) ^ lq7) << 3) + (col & 7)] = f2bf(acc[f][r] * inv);
      }
  }
  __syncthreads();
#pragma unroll
  for (int i = 0; i < 2; ++i) {
    int cid = i * 256 + t;
    int q = cid >> 3, ch = cid & 7;
    bf16x8 v = *(const bf16x8*)&smem[q * 64 + ((ch ^ (q & 7)) << 3)];
    *(bf16x8*)&O[(size_t)(b * S_LEN + qb + q) * 1024 + h * 64 + (ch << 3)] = v;
  }
}

extern "C" void kernel_launch(void* const* d_in, const int* in_sizes, int n_in,
                              void* d_out, int out_size, void* d_ws, size_t ws_size,
                              hipStream_t stream) {
  const float* queries = (const float*)d_in[0];
  const float* keys    = (const float*)d_in[1];
  const float* values  = (const float*)d_in[2];
  const float* Wq      = (const float*)d_in[3];
  const float* bq      = (const float*)d_in[4];
  const float* Wlk     = (const float*)d_in[5];
  const float* blk     = (const float*)d_in[6];
  const float* Wlv     = (const float*)d_in[7];
  const float* blv     = (const float*)d_in[8];
  const float* Wkr     = (const float*)d_in[9];
  const float* Wvr     = (const float*)d_in[10];
  const float* Wout    = (const float*)d_in[11];
  const float* bout    = (const float*)d_in[12];

  u16* ws = (u16*)d_ws;
  u16* WqBf  = ws; ws += (size_t)2048 * 2048;
  u16* WkrBf = ws; ws += 64 * 128;
  u16* WvrBf = ws; ws += 64 * 128;
  u16* WoutT = ws; ws += (size_t)2048 * 2048;
  u16* WlkT  = ws; ws += (size_t)1024 * 2048;
  u16* WlvT  = ws; ws += (size_t)1024 * 2048;
  u16* Wq2T  = ws; ws += (size_t)1024 * 2048;
  u16* W2T   = ws; ws += (size_t)2048 * 1024;
  float* bq2 = (float*)ws; ws += 2048;
  u16* Qp    = ws; ws += (size_t)4096 * 1024;
  u16* LKb   = ws; ws += (size_t)4096 * 1024;
  u16* LVb   = ws; ws += (size_t)4096 * 1024;
  u16* LVt   = ws; ws += (size_t)32 * 64 * S_LEN;
  u16* Ob    = ws; ws += (size_t)4096 * 1024;

  dim3 blk256(256);
  cast_w<<<dim3(2056), blk256, 0, stream>>>(Wq, Wkr, Wvr, WqBf, WkrBf, WvrBf);
  transpose_w<<<dim3(32, 32, 3), blk256, 0, stream>>>(Wlk, Wlv, Wout, WlkT, WlvT, WoutT);

  absorb_q<<<dim3(17, 16), blk256, 0, stream>>>(WkrBf, WqBf, Wq2T, bq, Wkr, bq2);
  absorb_o<<<dim3(16, 16), blk256, 0, stream>>>(WoutT, WvrBf, W2T);

  // proj: fp32 A LDS-staged (R12 schedule).  768 blocks = 3/CU.
  gemm_projf<<<dim3(768), blk256, 0, stream>>>(
      queries, keys, values, Wq2T, WlkT, WlvT, bq2, blk, blv, Qp, LKb, LVb);

  transpose_lv<<<dim3(32, 32), blk256, 0, stream>>>(LVb, LVt);

  mla_attn5<<<dim3(8, 128), blk256, 0, stream>>>(Qp, LKb, LVt, Ob);

  // out: N=2048 (nxl=4, 16 x-tiles), 32 panels * 16 = 512 blocks = 2/CU
  gemm_dp<<<dim3(512), blk256, 0, stream>>>(
      Ob, W2T, bout, (float*)d_out, 2048, 1024, 4);
}